// Round 1
// baseline (972.418 us; speedup 1.0000x reference)
//
#include <hip/hip_runtime.h>
#include <hip/hip_bf16.h>

#define B_ 2
#define N_ 2048
#define DIM_ 512
#define H_ 4
#define DH_ 128
#define DHID_ 512
#define CH_ 64
#define NC_ 32
#define BH_ 8

__device__ __forceinline__ float sigmoidf_(float x) { return 1.0f / (1.0f + expf(-x)); }
__device__ __forceinline__ float gelu_f(float x) {
    return x * 0.5f * (1.0f + erff(x * 0.7071067811865476f));
}
__device__ __forceinline__ float gelu_g(float x) {
    float cdf = 0.5f * (1.0f + erff(x * 0.7071067811865476f));
    float pdf = 0.3989422804014327f * expf(-0.5f * x * x);
    return cdf + x * pdf;
}

// ---------------------------------------------------------------- rms norm
__global__ __launch_bounds__(256) void rms_kernel(
    const float* __restrict__ seq, const float* __restrict__ gs,
    const float* __restrict__ gr, float* __restrict__ xs, float* __restrict__ xr)
{
    const int row = blockIdx.x;
    const int t = threadIdx.x;
    const float* x = seq + (size_t)row * DIM_;
    float v0 = x[t], v1 = x[t + 256];
    float ss = v0 * v0 + v1 * v1;
#pragma unroll
    for (int off = 32; off; off >>= 1) ss += __shfl_xor(ss, off);
    __shared__ float red[4];
    if ((t & 63) == 0) red[t >> 6] = ss;
    __syncthreads();
    float tot = red[0] + red[1] + red[2] + red[3];
    float r = rsqrtf(tot * (1.0f / DIM_) + 1e-6f);
    size_t o = (size_t)row * DIM_;
    xs[o + t] = v0 * r * gs[t];
    xs[o + t + 256] = v1 * r * gs[t + 256];
    xr[o + t] = v0 * r * gr[t];
    xr[o + t + 256] = v1 * r * gr[t + 256];
}

// ---------------------------------------------------------------- chunk pool
__global__ __launch_bounds__(256) void pooled_kernel(
    const float* __restrict__ xs, float* __restrict__ pooled)
{
    int idx = blockIdx.x * 256 + threadIdx.x;   // 32768
    int d = idx & 511;
    int ci = (idx >> 9) & 31;
    int b = idx >> 14;
    const float* base = xs + ((size_t)b * N_ + ci * CH_) * DIM_ + d;
    float s = 0.f;
#pragma unroll 8
    for (int c = 0; c < CH_; ++c) s += base[(size_t)c * DIM_];
    pooled[idx] = s * (1.0f / CH_);
}

// ---------------------------------------------------------------- generic 512-K GEMM
// A [4096,512] @ W [512,512]; SPLIT=1 scatters output to [BH,NC,CH,DH]
template <int SPLIT>
__global__ __launch_bounds__(256) void gemm512(
    const float* __restrict__ A, const float* __restrict__ W, float* __restrict__ out)
{
    const int bm = blockIdx.x;   // 64 row tiles of 64
    const int bn = blockIdx.y;   // 8 col tiles of 64
    __shared__ float As[16][65];
    __shared__ float Bs[16][65];
    const int t = threadIdx.x;
    const int tx = t & 15, ty = t >> 4;
    float acc[4][4];
#pragma unroll
    for (int i = 0; i < 4; ++i)
#pragma unroll
        for (int j = 0; j < 4; ++j) acc[i][j] = 0.f;
    const int row0 = bm * 64, col0 = bn * 64;
    for (int k0 = 0; k0 < 512; k0 += 16) {
#pragma unroll
        for (int i = 0; i < 4; ++i) {
            int idx = t + i * 256;
            int r = idx >> 4, kk = idx & 15;
            As[kk][r] = A[(size_t)(row0 + r) * 512 + k0 + kk];
        }
#pragma unroll
        for (int i = 0; i < 4; ++i) {
            int idx = t + i * 256;
            int kk = idx >> 6, c = idx & 63;
            Bs[kk][c] = W[(size_t)(k0 + kk) * 512 + col0 + c];
        }
        __syncthreads();
#pragma unroll
        for (int kk = 0; kk < 16; ++kk) {
            float av[4], bv[4];
#pragma unroll
            for (int i = 0; i < 4; ++i) av[i] = As[kk][ty * 4 + i];
#pragma unroll
            for (int j = 0; j < 4; ++j) bv[j] = Bs[kk][tx * 4 + j];
#pragma unroll
            for (int i = 0; i < 4; ++i)
#pragma unroll
                for (int j = 0; j < 4; ++j) acc[i][j] += av[i] * bv[j];
        }
        __syncthreads();
    }
#pragma unroll
    for (int i = 0; i < 4; ++i)
#pragma unroll
        for (int j = 0; j < 4; ++j) {
            int row = row0 + ty * 4 + i, col = col0 + tx * 4 + j;
            if (SPLIT) {
                int b = row >> 11, n = row & 2047, h = col >> 7, d = col & 127;
                out[((((size_t)(b * H_ + h) * NC_ + (n >> 6)) * CH_) + (n & 63)) * DH_ + d] = acc[i][j];
            } else {
                out[(size_t)row * 512 + col] = acc[i][j];
            }
        }
}

// ---------------------------------------------------------------- per-token / per-chunk gates
__global__ __launch_bounds__(256) void gates_kernel(
    const float* __restrict__ xs, const float* __restrict__ xr,
    const float* __restrict__ Wa, const float* __restrict__ ba,
    const float* __restrict__ Wg, float* __restrict__ lrb, float* __restrict__ gateb)
{
    const int t = threadIdx.x;
    const int wave = t >> 6, lane = t & 63;
    const int row = blockIdx.x * 4 + wave;
    const int b = row >> 11, n = row & 2047;
    const float* xsr = xs + (size_t)row * DIM_;
    const float* xrr = xr + (size_t)row * DIM_;
#pragma unroll
    for (int h = 0; h < H_; ++h) {
        float aA = 0.f, aG = 0.f;
        for (int d = lane; d < DIM_; d += 64) {
            aA += xsr[d] * Wa[d * H_ + h];
            aG += xrr[d] * Wg[d * H_ + h];
        }
#pragma unroll
        for (int off = 32; off; off >>= 1) {
            aA += __shfl_xor(aA, off);
            aG += __shfl_xor(aG, off);
        }
        if (lane == 0) {
            int bh = b * H_ + h;
            lrb[(size_t)bh * N_ + n] = sigmoidf_(aA + ba[h]);
            gateb[(size_t)bh * N_ + n] = sigmoidf_(aG);
        }
    }
}

__global__ __launch_bounds__(256) void ba_kernel(
    const float* __restrict__ pooled, const float* __restrict__ Wm,
    const float* __restrict__ Wd, const float* __restrict__ bd,
    float* __restrict__ beta, float* __restrict__ alpha)
{
    const int t = threadIdx.x;             // 256 = B*NC*H
    const int b = t >> 7, rem = t & 127, ci = rem >> 2, h = rem & 3;
    const float* p = pooled + ((size_t)b * NC_ + ci) * DIM_;
    float am = 0.f, ad = 0.f;
    for (int d = 0; d < DIM_; ++d) {
        float pv = p[d];
        am += pv * Wm[d * H_ + h];
        ad += pv * Wd[d * H_ + h];
    }
    int bh = b * H_ + h;
    beta[bh * NC_ + ci] = sigmoidf_(am);
    alpha[bh * NC_ + ci] = 1.0f - sigmoidf_(ad + bd[h]);
}

// ---------------------------------------------------------------- weight transposes (for coalesced bwd reads)
__global__ __launch_bounds__(256) void transpose_prep(
    const float* __restrict__ w1, const float* __restrict__ w2,
    float* __restrict__ w1T, float* __restrict__ w2T)
{
    int idx = blockIdx.x * 256 + threadIdx.x;   // 65536
    int j = idx >> 7, d = idx & 127;
    w1T[idx] = w1[(size_t)d * DHID_ + j];        // w1T[j][d]
    int d2 = idx >> 9, j2 = idx & 511;
    w2T[idx] = w2[(size_t)j2 * DH_ + d2];        // w2T[d][j]
}

// ---------------------------------------------------------------- per-chunk surprise gradients
// one block per (bh,chunk); grads taken at init weights (ref: inner vmap in_axes=(None,...))
__global__ __launch_bounds__(256, 1) void grad_kernel(
    const float* __restrict__ kbuf, const float* __restrict__ vbuf,
    const float* __restrict__ lrbuf, const float* __restrict__ memg,
    const float* __restrict__ w1, const float* __restrict__ w2,
    const float* __restrict__ w1T, const float* __restrict__ w2T,
    float* __restrict__ sg, float* __restrict__ sw1, float* __restrict__ sw2)
{
    const int blk = blockIdx.x;
    const int t = threadIdx.x;
    const int bh = blk >> 5, nc = blk & 31;
    const float* kc = kbuf + (size_t)blk * (CH_ * DH_);
    const float* vc = vbuf + (size_t)blk * (CH_ * DH_);
    const float* lrp = lrbuf + (size_t)bh * N_ + nc * CH_;

    __shared__ float x_s[CH_][DH_];   // raw k-chunk
    __shared__ float h_s[CH_][DH_];   // rms-normed * g
    __shared__ float e_s[CH_][DH_];   // dL/dpred
    __shared__ float t_s[CH_][DH_];   // a-tile / dz-tile scratch
    __shared__ float r_s[CH_];
    __shared__ float lr_s[CH_];
    __shared__ float g_s[DH_];

#pragma unroll
    for (int i = 0; i < 8; ++i) {
        int idx = t + i * 256;          // float4 units, 2048 total
        int c = idx >> 5, d4 = idx & 31;
        ((float4*)&x_s[c][0])[d4] = ((const float4*)kc)[idx];
    }
    if (t < DH_) g_s[t] = memg[t];
    if (t < CH_) lr_s[t] = lrp[t];
    __syncthreads();
    {
        int c = t >> 2, sub = t & 3;
        float ss = 0.f;
#pragma unroll
        for (int d = 0; d < 32; ++d) { float xv = x_s[c][sub * 32 + d]; ss += xv * xv; }
        ss += __shfl_xor(ss, 1);
        ss += __shfl_xor(ss, 2);
        if (sub == 0) r_s[c] = rsqrtf(ss * (1.0f / DH_) + 1e-6f);
    }
    __syncthreads();
#pragma unroll
    for (int i = 0; i < 32; ++i) {
        int idx = t + i * 256;
        int c = idx >> 7, d = idx & 127;
        h_s[c][d] = x_s[c][d] * r_s[c] * g_s[d];
    }
    __syncthreads();

    const int ty = t >> 5, tx = t & 31;     // rows c=ty*8+i, cols d/j = tx*4+j
    float yacc[8][4];
#pragma unroll
    for (int i = 0; i < 8; ++i)
#pragma unroll
        for (int j = 0; j < 4; ++j) yacc[i][j] = 0.f;

    // ---- pass 1: forward y = gelu(h@w1)@w2 ----
    for (int jt = 0; jt < 4; ++jt) {
        float z[8][4];
#pragma unroll
        for (int i = 0; i < 8; ++i)
#pragma unroll
            for (int j = 0; j < 4; ++j) z[i][j] = 0.f;
        for (int kk = 0; kk < DH_; ++kk) {
            float4 wv = *(const float4*)(w1 + (size_t)kk * DHID_ + jt * 128 + tx * 4);
#pragma unroll
            for (int i = 0; i < 8; ++i) {
                float hv = h_s[ty * 8 + i][kk];
                z[i][0] += hv * wv.x; z[i][1] += hv * wv.y;
                z[i][2] += hv * wv.z; z[i][3] += hv * wv.w;
            }
        }
#pragma unroll
        for (int i = 0; i < 8; ++i)
#pragma unroll
            for (int j = 0; j < 4; ++j) t_s[ty * 8 + i][tx * 4 + j] = gelu_f(z[i][j]);
        __syncthreads();
        for (int jl = 0; jl < 128; ++jl) {
            float4 wv = *(const float4*)(w2 + (size_t)(jt * 128 + jl) * DH_ + tx * 4);
#pragma unroll
            for (int i = 0; i < 8; ++i) {
                float av = t_s[ty * 8 + i][jl];
                yacc[i][0] += av * wv.x; yacc[i][1] += av * wv.y;
                yacc[i][2] += av * wv.z; yacc[i][3] += av * wv.w;
            }
        }
        __syncthreads();
    }
    // e = lr * 2/DH * (y + x - v)
#pragma unroll
    for (int i = 0; i < 8; ++i) {
        int c = ty * 8 + i;
        float4 vv = ((const float4*)vc)[c * 32 + tx];
        float sc = lr_s[c] * (2.0f / DH_);
        float4 o;
        o.x = sc * (yacc[i][0] + x_s[c][tx * 4 + 0] - vv.x);
        o.y = sc * (yacc[i][1] + x_s[c][tx * 4 + 1] - vv.y);
        o.z = sc * (yacc[i][2] + x_s[c][tx * 4 + 2] - vv.z);
        o.w = sc * (yacc[i][3] + x_s[c][tx * 4 + 3] - vv.w);
        *(float4*)&e_s[c][tx * 4] = o;
    }
    __syncthreads();

    // ---- pass 2: backward ----
    float dh[8][4];
#pragma unroll
    for (int i = 0; i < 8; ++i)
#pragma unroll
        for (int j = 0; j < 4; ++j) dh[i][j] = 0.f;

    for (int jt = 0; jt < 4; ++jt) {
        float z[8][4];
#pragma unroll
        for (int i = 0; i < 8; ++i)
#pragma unroll
            for (int j = 0; j < 4; ++j) z[i][j] = 0.f;
        for (int kk = 0; kk < DH_; ++kk) {
            float4 wv = *(const float4*)(w1 + (size_t)kk * DHID_ + jt * 128 + tx * 4);
#pragma unroll
            for (int i = 0; i < 8; ++i) {
                float hv = h_s[ty * 8 + i][kk];
                z[i][0] += hv * wv.x; z[i][1] += hv * wv.y;
                z[i][2] += hv * wv.z; z[i][3] += hv * wv.w;
            }
        }
#pragma unroll
        for (int i = 0; i < 8; ++i)
#pragma unroll
            for (int j = 0; j < 4; ++j) t_s[ty * 8 + i][tx * 4 + j] = gelu_f(z[i][j]);
        __syncthreads();
        // dw2[j][d] = sum_c a[c][j] e[c][d]  (store -grad)
        {
            float acc[16][4];
#pragma unroll
            for (int ii = 0; ii < 16; ++ii)
#pragma unroll
                for (int j = 0; j < 4; ++j) acc[ii][j] = 0.f;
            for (int c = 0; c < CH_; ++c) {
                float4 ev = *(const float4*)&e_s[c][tx * 4];
#pragma unroll
                for (int ii = 0; ii < 16; ++ii) {
                    float av = t_s[c][ty * 16 + ii];
                    acc[ii][0] += av * ev.x; acc[ii][1] += av * ev.y;
                    acc[ii][2] += av * ev.z; acc[ii][3] += av * ev.w;
                }
            }
            float* dst = sw2 + (size_t)blk * (DHID_ * DH_);
#pragma unroll
            for (int ii = 0; ii < 16; ++ii) {
                float4 o;
                o.x = -acc[ii][0]; o.y = -acc[ii][1]; o.z = -acc[ii][2]; o.w = -acc[ii][3];
                *(float4*)(dst + (size_t)(jt * 128 + ty * 16 + ii) * DH_ + tx * 4) = o;
            }
        }
        // da = e @ w2^T ; dz = da * gelu'(z)
        float dz[8][4];
#pragma unroll
        for (int i = 0; i < 8; ++i)
#pragma unroll
            for (int j = 0; j < 4; ++j) dz[i][j] = 0.f;
        for (int d = 0; d < DH_; ++d) {
            float4 wv = *(const float4*)(w2T + (size_t)d * DHID_ + jt * 128 + tx * 4);
#pragma unroll
            for (int i = 0; i < 8; ++i) {
                float ev = e_s[ty * 8 + i][d];
                dz[i][0] += ev * wv.x; dz[i][1] += ev * wv.y;
                dz[i][2] += ev * wv.z; dz[i][3] += ev * wv.w;
            }
        }
#pragma unroll
        for (int i = 0; i < 8; ++i)
#pragma unroll
            for (int j = 0; j < 4; ++j) dz[i][j] *= gelu_g(z[i][j]);
        __syncthreads();
#pragma unroll
        for (int i = 0; i < 8; ++i)
#pragma unroll
            for (int j = 0; j < 4; ++j) t_s[ty * 8 + i][tx * 4 + j] = dz[i][j];
        __syncthreads();
        // dw1[d][j] = sum_c h[c][d] dz[c][j]  (store -grad)
        {
            float acc[16][4];
#pragma unroll
            for (int ii = 0; ii < 16; ++ii)
#pragma unroll
                for (int j = 0; j < 4; ++j) acc[ii][j] = 0.f;
            for (int c = 0; c < CH_; ++c) {
                float4 dzv = *(const float4*)&t_s[c][tx * 4];
#pragma unroll
                for (int ii = 0; ii < 16; ++ii) {
                    float hv = h_s[c][ty * 16 + ii];
                    acc[ii][0] += hv * dzv.x; acc[ii][1] += hv * dzv.y;
                    acc[ii][2] += hv * dzv.z; acc[ii][3] += hv * dzv.w;
                }
            }
            float* dst = sw1 + (size_t)blk * (DH_ * DHID_);
#pragma unroll
            for (int ii = 0; ii < 16; ++ii) {
                float4 o;
                o.x = -acc[ii][0]; o.y = -acc[ii][1]; o.z = -acc[ii][2]; o.w = -acc[ii][3];
                *(float4*)(dst + (size_t)(ty * 16 + ii) * DHID_ + jt * 128 + tx * 4) = o;
            }
        }
        // dh += dz @ w1^T
        for (int jl = 0; jl < 128; ++jl) {
            float4 wv = *(const float4*)(w1T + (size_t)(jt * 128 + jl) * DH_ + tx * 4);
#pragma unroll
            for (int i = 0; i < 8; ++i) {
                float dzv = t_s[ty * 8 + i][jl];
                dh[i][0] += dzv * wv.x; dh[i][1] += dzv * wv.y;
                dh[i][2] += dzv * wv.z; dh[i][3] += dzv * wv.w;
            }
        }
        __syncthreads();
    }
    // dg[d] = sum_c dh[c][d] * x[c][d]*r[c]   (store -grad)
    {
        float p0 = 0.f, p1 = 0.f, p2 = 0.f, p3 = 0.f;
#pragma unroll
        for (int i = 0; i < 8; ++i) {
            int c = ty * 8 + i;
            float rr = r_s[c];
            p0 += dh[i][0] * x_s[c][tx * 4 + 0] * rr;
            p1 += dh[i][1] * x_s[c][tx * 4 + 1] * rr;
            p2 += dh[i][2] * x_s[c][tx * 4 + 2] * rr;
            p3 += dh[i][3] * x_s[c][tx * 4 + 3] * rr;
        }
        t_s[ty][tx * 4 + 0] = p0;
        t_s[ty][tx * 4 + 1] = p1;
        t_s[ty][tx * 4 + 2] = p2;
        t_s[ty][tx * 4 + 3] = p3;
        __syncthreads();
        if (t < DH_) {
            float s = 0.f;
#pragma unroll
            for (int rI = 0; rI < 8; ++rI) s += t_s[rI][t];
            sg[(size_t)blk * DH_ + t] = -s;
        }
    }
}

// ---------------------------------------------------------------- momentum + decay scans (in place)
// buf[bh][ci][el] holds surprise; after kernel it holds w_prev for chunk ci
__global__ __launch_bounds__(256) void scan_kernel(
    float* __restrict__ buf, const float* __restrict__ init,
    const float* __restrict__ beta, const float* __restrict__ alpha, int el_bits)
{
    size_t idx = (size_t)blockIdx.x * 256 + threadIdx.x;
    int bh = (int)(idx >> el_bits);
    int el = (int)(idx & (((size_t)1 << el_bits) - 1));
    size_t EL = (size_t)1 << el_bits;
    float w = init[el], m = 0.f;
    const float* bp = beta + bh * NC_;
    const float* ap = alpha + bh * NC_;
    float* base = buf + ((size_t)bh * NC_) * EL + el;
    for (int ci = 0; ci < NC_; ++ci) {
        float s = base[(size_t)ci * EL];
        base[(size_t)ci * EL] = w;           // w_prev for this chunk
        m = fmaf(bp[ci], m, s);
        w = fmaf(ap[ci], w, m);
    }
}

// ---------------------------------------------------------------- retrieval (forward with w_prev) + gate
__global__ __launch_bounds__(256, 1) void retrieve_kernel(
    const float* __restrict__ qbuf, const float* __restrict__ gatebuf,
    const float* __restrict__ sg, const float* __restrict__ sw1,
    const float* __restrict__ sw2, float* __restrict__ retg)
{
    const int blk = blockIdx.x;
    const int t = threadIdx.x;
    const int bh = blk >> 5, nc = blk & 31;
    const float* qc = qbuf + (size_t)blk * (CH_ * DH_);
    const float* w1p = sw1 + (size_t)blk * (DH_ * DHID_);
    const float* w2p = sw2 + (size_t)blk * (DHID_ * DH_);
    const float* gp = sg + (size_t)blk * DH_;

    __shared__ float x_s[CH_][DH_];
    __shared__ float h_s[CH_][DH_];
    __shared__ float t_s[CH_][DH_];
    __shared__ float r_s[CH_];
    __shared__ float g_s[DH_];

#pragma unroll
    for (int i = 0; i < 8; ++i) {
        int idx = t + i * 256;
        int c = idx >> 5, d4 = idx & 31;
        ((float4*)&x_s[c][0])[d4] = ((const float4*)qc)[idx];
    }
    if (t < DH_) g_s[t] = gp[t];
    __syncthreads();
    {
        int c = t >> 2, sub = t & 3;
        float ss = 0.f;
#pragma unroll
        for (int d = 0; d < 32; ++d) { float xv = x_s[c][sub * 32 + d]; ss += xv * xv; }
        ss += __shfl_xor(ss, 1);
        ss += __shfl_xor(ss, 2);
        if (sub == 0) r_s[c] = rsqrtf(ss * (1.0f / DH_) + 1e-6f);
    }
    __syncthreads();
#pragma unroll
    for (int i = 0; i < 32; ++i) {
        int idx = t + i * 256;
        int c = idx >> 7, d = idx & 127;
        h_s[c][d] = x_s[c][d] * r_s[c] * g_s[d];
    }
    __syncthreads();

    const int ty = t >> 5, tx = t & 31;
    float yacc[8][4];
#pragma unroll
    for (int i = 0; i < 8; ++i)
#pragma unroll
        for (int j = 0; j < 4; ++j) yacc[i][j] = 0.f;

    for (int jt = 0; jt < 4; ++jt) {
        float z[8][4];
#pragma unroll
        for (int i = 0; i < 8; ++i)
#pragma unroll
            for (int j = 0; j < 4; ++j) z[i][j] = 0.f;
        for (int kk = 0; kk < DH_; ++kk) {
            float4 wv = *(const float4*)(w1p + (size_t)kk * DHID_ + jt * 128 + tx * 4);
#pragma unroll
            for (int i = 0; i < 8; ++i) {
                float hv = h_s[ty * 8 + i][kk];
                z[i][0] += hv * wv.x; z[i][1] += hv * wv.y;
                z[i][2] += hv * wv.z; z[i][3] += hv * wv.w;
            }
        }
#pragma unroll
        for (int i = 0; i < 8; ++i)
#pragma unroll
            for (int j = 0; j < 4; ++j) t_s[ty * 8 + i][tx * 4 + j] = gelu_f(z[i][j]);
        __syncthreads();
        for (int jl = 0; jl < 128; ++jl) {
            float4 wv = *(const float4*)(w2p + (size_t)(jt * 128 + jl) * DH_ + tx * 4);
#pragma unroll
            for (int i = 0; i < 8; ++i) {
                float av = t_s[ty * 8 + i][jl];
                yacc[i][0] += av * wv.x; yacc[i][1] += av * wv.y;
                yacc[i][2] += av * wv.z; yacc[i][3] += av * wv.w;
            }
        }
        __syncthreads();
    }
    const int b = bh >> 2, hh = bh & 3;
#pragma unroll
    for (int i = 0; i < 8; ++i) {
        int c = ty * 8 + i, n = nc * CH_ + c;
        float gv = gatebuf[(size_t)bh * N_ + n];
        float4 o;
        o.x = (yacc[i][0] + x_s[c][tx * 4 + 0]) * gv;
        o.y = (yacc[i][1] + x_s[c][tx * 4 + 1]) * gv;
        o.z = (yacc[i][2] + x_s[c][tx * 4 + 2]) * gv;
        o.w = (yacc[i][3] + x_s[c][tx * 4 + 3]) * gv;
        *(float4*)(retg + ((size_t)(b * N_ + n)) * 512 + hh * 128 + tx * 4) = o;
    }
}

// ---------------------------------------------------------------- launch
extern "C" void kernel_launch(void* const* d_in, const int* in_sizes, int n_in,
                              void* d_out, int out_size, void* d_ws, size_t ws_size,
                              hipStream_t stream) {
    const float* seq     = (const float*)d_in[0];
    const float* g_store = (const float*)d_in[1];
    const float* g_retr  = (const float*)d_in[2];
    const float* Wq = (const float*)d_in[3];
    const float* Wk = (const float*)d_in[4];
    const float* Wv = (const float*)d_in[5];
    const float* Wa = (const float*)d_in[6];
    const float* ba = (const float*)d_in[7];
    const float* Wm = (const float*)d_in[8];
    const float* Wd = (const float*)d_in[9];
    const float* bd = (const float*)d_in[10];
    const float* Wg = (const float*)d_in[11];
    const float* Wc = (const float*)d_in[12];
    const float* memg = (const float*)d_in[13];
    const float* w1 = (const float*)d_in[14];
    const float* w2 = (const float*)d_in[15];
    float* out = (float*)d_out;

    float* p = (float*)d_ws;
    float* xs = p;     p += (size_t)B_ * N_ * DIM_;
    float* xr = p;     p += (size_t)B_ * N_ * DIM_;
    float* kb = p;     p += (size_t)B_ * N_ * DIM_;
    float* vb = p;     p += (size_t)B_ * N_ * DIM_;
    float* qb = p;     p += (size_t)B_ * N_ * DIM_;
    float* lrb = p;    p += (size_t)BH_ * N_;
    float* gateb = p;  p += (size_t)BH_ * N_;
    float* pooled = p; p += (size_t)B_ * NC_ * DIM_;
    float* beta = p;   p += BH_ * NC_;
    float* alpha = p;  p += BH_ * NC_;
    float* w1T = p;    p += DH_ * DHID_;
    float* w2T = p;    p += DH_ * DHID_;
    float* sgb = p;    p += (size_t)BH_ * NC_ * DH_;
    float* sw1 = p;    p += (size_t)BH_ * NC_ * DH_ * DHID_;
    float* sw2 = p;    p += (size_t)BH_ * NC_ * DH_ * DHID_;
    float* retg = xs;  // xs is dead by retrieval time — reuse

    rms_kernel<<<B_ * N_, 256, 0, stream>>>(seq, g_store, g_retr, xs, xr);
    pooled_kernel<<<(B_ * NC_ * DIM_) / 256, 256, 0, stream>>>(xs, pooled);
    gemm512<1><<<dim3(64, 8), 256, 0, stream>>>(xr, Wq, qb);
    gemm512<1><<<dim3(64, 8), 256, 0, stream>>>(xs, Wk, kb);
    gemm512<1><<<dim3(64, 8), 256, 0, stream>>>(xs, Wv, vb);
    gates_kernel<<<(B_ * N_) / 4, 256, 0, stream>>>(xs, xr, Wa, ba, Wg, lrb, gateb);
    ba_kernel<<<1, 256, 0, stream>>>(pooled, Wm, Wd, bd, beta, alpha);
    transpose_prep<<<256, 256, 0, stream>>>(w1, w2, w1T, w2T);
    grad_kernel<<<BH_ * NC_, 256, 0, stream>>>(kb, vb, lrb, memg, w1, w2, w1T, w2T,
                                               sgb, sw1, sw2);
    scan_kernel<<<(BH_ * DH_ * DHID_) / 256, 256, 0, stream>>>(sw1, w1, beta, alpha, 16);
    scan_kernel<<<(BH_ * DH_ * DHID_) / 256, 256, 0, stream>>>(sw2, w2, beta, alpha, 16);
    scan_kernel<<<(BH_ * DH_) / 256, 256, 0, stream>>>(sgb, memg, beta, alpha, 7);
    retrieve_kernel<<<BH_ * NC_, 256, 0, stream>>>(qb, gateb, sgb, sw1, sw2, retg);
    gemm512<0><<<dim3(64, 8), 256, 0, stream>>>(retg, Wc, out);
}

// Round 2
// 387.214 us; speedup vs baseline: 2.5113x; 2.5113x over previous
//
#include <hip/hip_runtime.h>
#include <hip/hip_bf16.h>

#define B_ 2
#define N_ 2048
#define DIM_ 512
#define H_ 4
#define DH_ 128
#define DHID_ 512
#define CH_ 64
#define NC_ 32
#define BH_ 8

typedef __bf16 bf16x8 __attribute__((ext_vector_type(8)));
typedef float f32x4 __attribute__((ext_vector_type(4)));

__device__ __forceinline__ f32x4 MFMA(bf16x8 a, bf16x8 b, f32x4 c) {
    return __builtin_amdgcn_mfma_f32_16x16x32_bf16(a, b, c, 0, 0, 0);
}
__device__ __forceinline__ bf16x8 ld8(const __bf16* p) { return *(const bf16x8*)p; }

__device__ __forceinline__ float sigmoidf_(float x) { return 1.0f / (1.0f + expf(-x)); }
__device__ __forceinline__ float gelu_f(float x) {
    return x * 0.5f * (1.0f + erff(x * 0.7071067811865476f));
}
__device__ __forceinline__ float gelu_g(float x) {
    float cdf = 0.5f * (1.0f + erff(x * 0.7071067811865476f));
    float pdf = 0.3989422804014327f * expf(-0.5f * x * x);
    return cdf + x * pdf;
}

// ---------------------------------------------------------------- rms norm (+bf16 copies)
__global__ __launch_bounds__(256) void rms_kernel(
    const float* __restrict__ seq, const float* __restrict__ gs,
    const float* __restrict__ gr, float* __restrict__ xs, float* __restrict__ xr,
    __bf16* __restrict__ xsb, __bf16* __restrict__ xrb)
{
    const int row = blockIdx.x;
    const int t = threadIdx.x;
    const float* x = seq + (size_t)row * DIM_;
    float v0 = x[t], v1 = x[t + 256];
    float ss = v0 * v0 + v1 * v1;
#pragma unroll
    for (int off = 32; off; off >>= 1) ss += __shfl_xor(ss, off);
    __shared__ float red[4];
    if ((t & 63) == 0) red[t >> 6] = ss;
    __syncthreads();
    float tot = red[0] + red[1] + red[2] + red[3];
    float r = rsqrtf(tot * (1.0f / DIM_) + 1e-6f);
    size_t o = (size_t)row * DIM_;
    float a0 = v0 * r * gs[t], a1 = v1 * r * gs[t + 256];
    float b0 = v0 * r * gr[t], b1 = v1 * r * gr[t + 256];
    xs[o + t] = a0; xs[o + t + 256] = a1;
    xr[o + t] = b0; xr[o + t + 256] = b1;
    xsb[o + t] = (__bf16)a0; xsb[o + t + 256] = (__bf16)a1;
    xrb[o + t] = (__bf16)b0; xrb[o + t + 256] = (__bf16)b1;
}

// ---------------------------------------------------------------- chunk pool
__global__ __launch_bounds__(256) void pooled_kernel(
    const float* __restrict__ xs, float* __restrict__ pooled)
{
    int idx = blockIdx.x * 256 + threadIdx.x;
    int d = idx & 511;
    int ci = (idx >> 9) & 31;
    int b = idx >> 14;
    const float* base = xs + ((size_t)b * N_ + ci * CH_) * DIM_ + d;
    float s = 0.f;
#pragma unroll 8
    for (int c = 0; c < CH_; ++c) s += base[(size_t)c * DIM_];
    pooled[idx] = s * (1.0f / CH_);
}

// ---------------------------------------------------------------- gates
__global__ __launch_bounds__(256) void gates_kernel(
    const float* __restrict__ xs, const float* __restrict__ xr,
    const float* __restrict__ Wa, const float* __restrict__ ba,
    const float* __restrict__ Wg, float* __restrict__ lrb, float* __restrict__ gateb)
{
    const int t = threadIdx.x;
    const int wave = t >> 6, lane = t & 63;
    const int row = blockIdx.x * 4 + wave;
    const int b = row >> 11, n = row & 2047;
    const float* xsr = xs + (size_t)row * DIM_;
    const float* xrr = xr + (size_t)row * DIM_;
#pragma unroll
    for (int h = 0; h < H_; ++h) {
        float aA = 0.f, aG = 0.f;
        for (int d = lane; d < DIM_; d += 64) {
            aA += xsr[d] * Wa[d * H_ + h];
            aG += xrr[d] * Wg[d * H_ + h];
        }
#pragma unroll
        for (int off = 32; off; off >>= 1) {
            aA += __shfl_xor(aA, off);
            aG += __shfl_xor(aG, off);
        }
        if (lane == 0) {
            int bh = b * H_ + h;
            lrb[(size_t)bh * N_ + n] = sigmoidf_(aA + ba[h]);
            gateb[(size_t)bh * N_ + n] = sigmoidf_(aG);
        }
    }
}

__global__ __launch_bounds__(256) void ba_kernel(
    const float* __restrict__ pooled, const float* __restrict__ Wm,
    const float* __restrict__ Wd, const float* __restrict__ bd,
    float* __restrict__ beta, float* __restrict__ alpha)
{
    const int t = threadIdx.x;
    const int b = t >> 7, rem = t & 127, ci = rem >> 2, h = rem & 3;
    const float* p = pooled + ((size_t)b * NC_ + ci) * DIM_;
    float am = 0.f, ad = 0.f;
    for (int d = 0; d < DIM_; ++d) {
        float pv = p[d];
        am += pv * Wm[d * H_ + h];
        ad += pv * Wd[d * H_ + h];
    }
    int bh = b * H_ + h;
    beta[bh * NC_ + ci] = sigmoidf_(am);
    alpha[bh * NC_ + ci] = 1.0f - sigmoidf_(ad + bd[h]);
}

// ---------------------------------------------------------------- weight prep: bf16 copies + transposes
__global__ __launch_bounds__(256) void prep_kernel(
    const float* __restrict__ w1, const float* __restrict__ w2,
    const float* __restrict__ Wq, const float* __restrict__ Wk,
    const float* __restrict__ Wv, const float* __restrict__ Wc,
    __bf16* __restrict__ w1b, __bf16* __restrict__ w1Tb,
    __bf16* __restrict__ w2b, __bf16* __restrict__ w2Tb,
    __bf16* __restrict__ WqT, __bf16* __restrict__ WkT,
    __bf16* __restrict__ WvT, __bf16* __restrict__ WcT)
{
    int idx = blockIdx.x * 256 + threadIdx.x;   // 262144
    if (idx < 65536) {
        w1b[idx] = (__bf16)w1[idx];                       // [d][j]
        int j = idx >> 7, d = idx & 127;
        w1Tb[idx] = (__bf16)w1[(size_t)d * DHID_ + j];    // [j][d]
        w2b[idx] = (__bf16)w2[idx];                       // [j][d]
        int d2 = idx >> 9, j2 = idx & 511;
        w2Tb[idx] = (__bf16)w2[(size_t)j2 * DH_ + d2];    // [d][j]
    }
    int n = idx >> 9, k = idx & 511;                      // WT[n][k] = W[k][n]
    WqT[idx] = (__bf16)Wq[(size_t)k * 512 + n];
    WkT[idx] = (__bf16)Wk[(size_t)k * 512 + n];
    WvT[idx] = (__bf16)Wv[(size_t)k * 512 + n];
    WcT[idx] = (__bf16)Wc[(size_t)k * 512 + n];
}

// ---------------------------------------------------------------- MFMA GEMM: C[4096,512] = A_bf16 @ W (via WT_bf16)
template <int SPLIT>
__global__ __launch_bounds__(256, 4) void gemm_bf(
    const __bf16* __restrict__ A, const __bf16* __restrict__ WT, float* __restrict__ out)
{
    const int t = threadIdx.x;
    const int wave = t >> 6, lane = t & 63;
    const int lrow = lane & 15, lgrp = lane >> 4;
    const int c0 = blockIdx.x * 64 + wave * 16;
    const int col0 = blockIdx.y * 64;
    f32x4 acc[4];
#pragma unroll
    for (int i = 0; i < 4; ++i) acc[i] = (f32x4)0.f;
    const __bf16* ar = A + (size_t)(c0 + lrow) * 512;
#pragma unroll 4
    for (int k0 = 0; k0 < 512; k0 += 32) {
        bf16x8 av = ld8(ar + k0 + lgrp * 8);
#pragma unroll
        for (int ct = 0; ct < 4; ++ct) {
            bf16x8 bv = ld8(WT + (size_t)(col0 + ct * 16 + lrow) * 512 + k0 + lgrp * 8);
            acc[ct] = MFMA(av, bv, acc[ct]);
        }
    }
#pragma unroll
    for (int ct = 0; ct < 4; ++ct)
#pragma unroll
        for (int r = 0; r < 4; ++r) {
            int row = c0 + lgrp * 4 + r, col = col0 + ct * 16 + lrow;
            if (SPLIT) {
                int b = row >> 11, n = row & 2047, h = col >> 7, d = col & 127;
                out[((((size_t)(b * H_ + h) * NC_ + (n >> 6)) * CH_) + (n & 63)) * DH_ + d] = acc[ct][r];
            } else {
                out[(size_t)row * 512 + col] = acc[ct][r];
            }
        }
}

// ---------------------------------------------------------------- per-chunk surprise gradients (MFMA)
__global__ __launch_bounds__(512, 2) void grad_kernel(
    const float* __restrict__ kbuf, const float* __restrict__ vbuf,
    const float* __restrict__ lrbuf, const float* __restrict__ memg,
    const __bf16* __restrict__ w1b, const __bf16* __restrict__ w1Tb,
    const __bf16* __restrict__ w2b, const __bf16* __restrict__ w2Tb,
    float* __restrict__ sg, __bf16* __restrict__ sw1, __bf16* __restrict__ sw2)
{
    const int blk = blockIdx.x;
    const int t = threadIdx.x;
    const int w = t >> 6, lane = t & 63;
    const int lrow = lane & 15, lgrp = lane >> 4;
    const int bh = blk >> 5, nc = blk & 31;
    const float* kc = kbuf + (size_t)blk * (CH_ * DH_);
    const float* vc = vbuf + (size_t)blk * (CH_ * DH_);
    const float* lrp = lrbuf + (size_t)bh * N_ + nc * CH_;
    __bf16* sw1_blk = sw1 + (size_t)blk * (DHID_ * DH_);
    __bf16* sw2_blk = sw2 + (size_t)blk * (DHID_ * DH_);

    __shared__ __bf16 h_s[64][136];
    __shared__ __bf16 e_s[64][136];
    __shared__ __bf16 a_s[64][136];
    __shared__ __bf16 dz_s[64][136];
    __shared__ __bf16 hT_s[128][72];
    __shared__ __bf16 eT_s[128][72];
    __shared__ __bf16 aT_s[128][72];
    __shared__ __bf16 dzT_s[128][72];
    __shared__ float r_s[64];
    __shared__ float lr_s[64];
    __shared__ float g_s[128];

    // ---- phase A: load k-chunk, rms, h = x*r*g ----
    if (t < 128) g_s[t] = memg[t];
    if (t < 64) lr_s[t] = lrp[t];
    {
        const int c = t >> 3, dblk = t & 7, d0 = dblk * 16;
        float xv[16];
        float ss = 0.f;
#pragma unroll
        for (int i = 0; i < 4; ++i) {
            float4 f = *(const float4*)(kc + (size_t)c * DH_ + d0 + i * 4);
            xv[i * 4 + 0] = f.x; xv[i * 4 + 1] = f.y; xv[i * 4 + 2] = f.z; xv[i * 4 + 3] = f.w;
            ss += f.x * f.x + f.y * f.y + f.z * f.z + f.w * f.w;
        }
        ss += __shfl_xor(ss, 1); ss += __shfl_xor(ss, 2); ss += __shfl_xor(ss, 4);
        float r = rsqrtf(ss * (1.0f / DH_) + 1e-6f);
        if (dblk == 0) r_s[c] = r;
        __syncthreads();   // g_s visible
#pragma unroll
        for (int i = 0; i < 16; ++i)
            h_s[c][d0 + i] = (__bf16)(xv[i] * r * g_s[d0 + i]);
    }
    __syncthreads();
    // hT fill
    {
        const int d = t >> 2, c0 = (t & 3) * 16;
#pragma unroll
        for (int i = 0; i < 16; ++i) hT_s[d][c0 + i] = h_s[c0 + i][d];
    }
    __syncthreads();

    // ---- pass 1: forward ----
    const int cs = w & 3, half = w >> 2;
    const int c0w = cs * 16, off64 = half * 64;
    f32x4 yacc[4];
#pragma unroll
    for (int i = 0; i < 4; ++i) yacc[i] = (f32x4)0.f;

    for (int jt = 0; jt < 4; ++jt) {
        // z[c-strip, 64 cols] = h @ w1
        f32x4 zacc[4];
#pragma unroll
        for (int i = 0; i < 4; ++i) zacc[i] = (f32x4)0.f;
#pragma unroll
        for (int kt = 0; kt < 4; ++kt) {
            bf16x8 av = ld8(&h_s[c0w + lrow][kt * 32 + lgrp * 8]);
#pragma unroll
            for (int ct = 0; ct < 4; ++ct) {
                int j = jt * 128 + off64 + ct * 16 + lrow;
                bf16x8 bv = ld8(w1Tb + (size_t)j * 128 + kt * 32 + lgrp * 8);
                zacc[ct] = MFMA(av, bv, zacc[ct]);
            }
        }
#pragma unroll
        for (int ct = 0; ct < 4; ++ct)
#pragma unroll
            for (int r = 0; r < 4; ++r)
                a_s[c0w + lgrp * 4 + r][off64 + ct * 16 + lrow] = (__bf16)gelu_f(zacc[ct][r]);
        __syncthreads();
        // y += a @ w2  (c-strip, d-half)
#pragma unroll
        for (int kt = 0; kt < 4; ++kt) {
            bf16x8 av = ld8(&a_s[c0w + lrow][kt * 32 + lgrp * 8]);
#pragma unroll
            for (int ct = 0; ct < 4; ++ct) {
                int d = off64 + ct * 16 + lrow;
                bf16x8 bv = ld8(w2Tb + (size_t)d * 512 + jt * 128 + kt * 32 + lgrp * 8);
                yacc[ct] = MFMA(av, bv, yacc[ct]);
            }
        }
        __syncthreads();
    }
    // e = lr*2/DH*(y + x - v)
#pragma unroll
    for (int ct = 0; ct < 4; ++ct)
#pragma unroll
        for (int r = 0; r < 4; ++r) {
            int c = c0w + lgrp * 4 + r, d = off64 + ct * 16 + lrow;
            float xvv = kc[(size_t)c * DH_ + d];
            float vvv = vc[(size_t)c * DH_ + d];
            float e = lr_s[c] * (2.0f / DH_) * (yacc[ct][r] + xvv - vvv);
            e_s[c][d] = (__bf16)e;
            eT_s[d][c] = (__bf16)e;
        }
    __syncthreads();

    // ---- pass 2: backward ----
    const int jl0 = w * 16;      // j-strip / d-strip of this wave
    f32x4 dhacc[4];
#pragma unroll
    for (int i = 0; i < 4; ++i) dhacc[i] = (f32x4)0.f;

    for (int jt = 0; jt < 4; ++jt) {
        // zT[j-strip, c] = w1T @ hT ; daT = w2 @ eT (same tiling)
        f32x4 ztacc[4], dtacc[4];
#pragma unroll
        for (int i = 0; i < 4; ++i) { ztacc[i] = (f32x4)0.f; dtacc[i] = (f32x4)0.f; }
#pragma unroll
        for (int kt = 0; kt < 4; ++kt) {
            bf16x8 avz = ld8(w1Tb + (size_t)(jt * 128 + jl0 + lrow) * 128 + kt * 32 + lgrp * 8);
            bf16x8 avd = ld8(w2b  + (size_t)(jt * 128 + jl0 + lrow) * 128 + kt * 32 + lgrp * 8);
#pragma unroll
            for (int ct = 0; ct < 4; ++ct) {
                bf16x8 bvh = ld8(&h_s[ct * 16 + lrow][kt * 32 + lgrp * 8]);
                bf16x8 bve = ld8(&e_s[ct * 16 + lrow][kt * 32 + lgrp * 8]);
                ztacc[ct] = MFMA(avz, bvh, ztacc[ct]);
                dtacc[ct] = MFMA(avd, bve, dtacc[ct]);
            }
        }
#pragma unroll
        for (int ct = 0; ct < 4; ++ct)
#pragma unroll
            for (int r = 0; r < 4; ++r) {
                int j = jl0 + lgrp * 4 + r, c = ct * 16 + lrow;
                float zt = ztacc[ct][r];
                aT_s[j][c] = (__bf16)gelu_f(zt);
                float dzt = dtacc[ct][r] * gelu_g(zt);
                dzT_s[j][c] = (__bf16)dzt;
                dz_s[c][j] = (__bf16)dzt;
            }
        __syncthreads();
        // dw1T[j-strip, 128 d] = dzT @ h   (K=c)
        {
            f32x4 wacc[8];
#pragma unroll
            for (int i = 0; i < 8; ++i) wacc[i] = (f32x4)0.f;
#pragma unroll
            for (int kt = 0; kt < 2; ++kt) {
                bf16x8 av = ld8(&dzT_s[jl0 + lrow][kt * 32 + lgrp * 8]);
#pragma unroll
                for (int ct = 0; ct < 8; ++ct) {
                    bf16x8 bv = ld8(&hT_s[ct * 16 + lrow][kt * 32 + lgrp * 8]);
                    wacc[ct] = MFMA(av, bv, wacc[ct]);
                }
            }
#pragma unroll
            for (int ct = 0; ct < 8; ++ct)
#pragma unroll
                for (int r = 0; r < 4; ++r) {
                    int jg = jt * 128 + jl0 + lgrp * 4 + r, d = ct * 16 + lrow;
                    sw1_blk[(size_t)jg * 128 + d] = (__bf16)(-wacc[ct][r]);
                }
        }
        // dw2T[d-strip, 128 j] = eT @ a   (K=c)
        {
            f32x4 wacc[8];
#pragma unroll
            for (int i = 0; i < 8; ++i) wacc[i] = (f32x4)0.f;
#pragma unroll
            for (int kt = 0; kt < 2; ++kt) {
                bf16x8 av = ld8(&eT_s[jl0 + lrow][kt * 32 + lgrp * 8]);
#pragma unroll
                for (int ct = 0; ct < 8; ++ct) {
                    bf16x8 bv = ld8(&aT_s[ct * 16 + lrow][kt * 32 + lgrp * 8]);
                    wacc[ct] = MFMA(av, bv, wacc[ct]);
                }
            }
#pragma unroll
            for (int ct = 0; ct < 8; ++ct)
#pragma unroll
                for (int r = 0; r < 4; ++r) {
                    int d = jl0 + lgrp * 4 + r, jg = jt * 128 + ct * 16 + lrow;
                    sw2_blk[(size_t)d * 512 + jg] = (__bf16)(-wacc[ct][r]);
                }
        }
        // dhT[d-strip, c] += w1 @ dz   (K=j local)
#pragma unroll
        for (int kt = 0; kt < 4; ++kt) {
            bf16x8 av = ld8(w1b + (size_t)(jl0 + lrow) * 512 + jt * 128 + kt * 32 + lgrp * 8);
#pragma unroll
            for (int ct = 0; ct < 4; ++ct) {
                bf16x8 bv = ld8(&dz_s[ct * 16 + lrow][kt * 32 + lgrp * 8]);
                dhacc[ct] = MFMA(av, bv, dhacc[ct]);
            }
        }
        __syncthreads();
    }
    // dg[d] = sum_c dhT[d][c]*h[c][d] / g[d]   (x*r = h/g; memg==1 in practice)
    {
        float s[4] = {0.f, 0.f, 0.f, 0.f};
#pragma unroll
        for (int ct = 0; ct < 4; ++ct)
#pragma unroll
            for (int r = 0; r < 4; ++r) {
                int d = jl0 + lgrp * 4 + r, c = ct * 16 + lrow;
                s[r] += dhacc[ct][r] * (float)hT_s[d][c];
            }
#pragma unroll
        for (int r = 0; r < 4; ++r) {
            s[r] += __shfl_xor(s[r], 1); s[r] += __shfl_xor(s[r], 2);
            s[r] += __shfl_xor(s[r], 4); s[r] += __shfl_xor(s[r], 8);
        }
        if (lrow == 0) {
#pragma unroll
            for (int r = 0; r < 4; ++r) {
                int d = jl0 + lgrp * 4 + r;
                sg[(size_t)blk * DH_ + d] = -s[r] / g_s[d];
            }
        }
    }
}

// ---------------------------------------------------------------- scans
__global__ __launch_bounds__(256) void scan_bf(
    __bf16* __restrict__ buf, const __bf16* __restrict__ init,
    const float* __restrict__ beta, const float* __restrict__ alpha)
{
    int idx = blockIdx.x * 256 + threadIdx.x;    // BH*65536
    int bh = idx >> 16, el = idx & 65535;
    float wv = (float)init[el], m = 0.f;
    const float* bp = beta + bh * NC_;
    const float* ap = alpha + bh * NC_;
    __bf16* base = buf + ((size_t)bh * NC_) * 65536 + el;
    for (int ci = 0; ci < NC_; ++ci) {
        float s = (float)base[(size_t)ci * 65536];
        base[(size_t)ci * 65536] = (__bf16)wv;
        m = fmaf(bp[ci], m, s);
        wv = fmaf(ap[ci], wv, m);
    }
}

__global__ __launch_bounds__(256) void scan_g(
    float* __restrict__ buf, const float* __restrict__ init,
    const float* __restrict__ beta, const float* __restrict__ alpha)
{
    int idx = blockIdx.x * 256 + threadIdx.x;    // BH*128
    int bh = idx >> 7, el = idx & 127;
    float wv = init[el], m = 0.f;
    const float* bp = beta + bh * NC_;
    const float* ap = alpha + bh * NC_;
    float* base = buf + ((size_t)bh * NC_) * 128 + el;
    for (int ci = 0; ci < NC_; ++ci) {
        float s = base[(size_t)ci * 128];
        base[(size_t)ci * 128] = wv;
        m = fmaf(bp[ci], m, s);
        wv = fmaf(ap[ci], wv, m);
    }
}

// ---------------------------------------------------------------- retrieval (MFMA forward) + gate
__global__ __launch_bounds__(256, 2) void retrieve_kernel(
    const float* __restrict__ qbuf, const float* __restrict__ gatebuf,
    const float* __restrict__ sg, const __bf16* __restrict__ sw1,
    const __bf16* __restrict__ sw2, __bf16* __restrict__ retgb)
{
    const int blk = blockIdx.x;
    const int t = threadIdx.x;
    const int w = t >> 6, lane = t & 63;
    const int lrow = lane & 15, lgrp = lane >> 4;
    const int bh = blk >> 5, nc = blk & 31;
    const float* qc = qbuf + (size_t)blk * (CH_ * DH_);
    const __bf16* w1p = sw1 + (size_t)blk * (DHID_ * DH_);
    const __bf16* w2p = sw2 + (size_t)blk * (DHID_ * DH_);
    const float* gp = sg + (size_t)blk * DH_;

    __shared__ __bf16 h_s[64][136];
    __shared__ __bf16 a_s[64][136];
    __shared__ float g_s[128];

    if (t < 128) g_s[t] = gp[t];
    {
        const int c = t >> 2, dblk = t & 3, d0 = dblk * 32;
        float xv[32];
        float ss = 0.f;
#pragma unroll
        for (int i = 0; i < 8; ++i) {
            float4 f = *(const float4*)(qc + (size_t)c * DH_ + d0 + i * 4);
            xv[i * 4 + 0] = f.x; xv[i * 4 + 1] = f.y; xv[i * 4 + 2] = f.z; xv[i * 4 + 3] = f.w;
            ss += f.x * f.x + f.y * f.y + f.z * f.z + f.w * f.w;
        }
        ss += __shfl_xor(ss, 1); ss += __shfl_xor(ss, 2);
        float r = rsqrtf(ss * (1.0f / DH_) + 1e-6f);
        __syncthreads();   // g_s visible
#pragma unroll
        for (int i = 0; i < 32; ++i)
            h_s[c][d0 + i] = (__bf16)(xv[i] * r * g_s[d0 + i]);
    }
    __syncthreads();

    const int c0w = w * 16;
    f32x4 yacc[8];
#pragma unroll
    for (int i = 0; i < 8; ++i) yacc[i] = (f32x4)0.f;

    for (int jt = 0; jt < 4; ++jt) {
        f32x4 zacc[8];
#pragma unroll
        for (int i = 0; i < 8; ++i) zacc[i] = (f32x4)0.f;
#pragma unroll
        for (int kt = 0; kt < 4; ++kt) {
            bf16x8 av = ld8(&h_s[c0w + lrow][kt * 32 + lgrp * 8]);
#pragma unroll
            for (int ct = 0; ct < 8; ++ct) {
                int j = jt * 128 + ct * 16 + lrow;
                bf16x8 bv = ld8(w1p + (size_t)j * 128 + kt * 32 + lgrp * 8);
                zacc[ct] = MFMA(av, bv, zacc[ct]);
            }
        }
#pragma unroll
        for (int ct = 0; ct < 8; ++ct)
#pragma unroll
            for (int r = 0; r < 4; ++r)
                a_s[c0w + lgrp * 4 + r][ct * 16 + lrow] = (__bf16)gelu_f(zacc[ct][r]);
        __syncthreads();
#pragma unroll
        for (int kt = 0; kt < 4; ++kt) {
            bf16x8 av = ld8(&a_s[c0w + lrow][kt * 32 + lgrp * 8]);
#pragma unroll
            for (int ct = 0; ct < 8; ++ct) {
                int d = ct * 16 + lrow;
                bf16x8 bv = ld8(w2p + (size_t)d * 512 + jt * 128 + kt * 32 + lgrp * 8);
                yacc[ct] = MFMA(av, bv, yacc[ct]);
            }
        }
        __syncthreads();
    }
    const int b = bh >> 2, hh = bh & 3;
#pragma unroll
    for (int ct = 0; ct < 8; ++ct)
#pragma unroll
        for (int r = 0; r < 4; ++r) {
            int c = c0w + lgrp * 4 + r, d = ct * 16 + lrow;
            int n = nc * CH_ + c;
            float q = qc[(size_t)c * DH_ + d];
            float gv = gatebuf[(size_t)bh * N_ + n];
            retgb[((size_t)(b * N_ + n)) * 512 + hh * 128 + d] = (__bf16)((yacc[ct][r] + q) * gv);
        }
}

// ---------------------------------------------------------------- launch
extern "C" void kernel_launch(void* const* d_in, const int* in_sizes, int n_in,
                              void* d_out, int out_size, void* d_ws, size_t ws_size,
                              hipStream_t stream) {
    const float* seq     = (const float*)d_in[0];
    const float* g_store = (const float*)d_in[1];
    const float* g_retr  = (const float*)d_in[2];
    const float* Wq = (const float*)d_in[3];
    const float* Wk = (const float*)d_in[4];
    const float* Wv = (const float*)d_in[5];
    const float* Wa = (const float*)d_in[6];
    const float* ba = (const float*)d_in[7];
    const float* Wm = (const float*)d_in[8];
    const float* Wd = (const float*)d_in[9];
    const float* bd = (const float*)d_in[10];
    const float* Wg = (const float*)d_in[11];
    const float* Wc = (const float*)d_in[12];
    const float* memg = (const float*)d_in[13];
    const float* w1 = (const float*)d_in[14];
    const float* w2 = (const float*)d_in[15];
    float* out = (float*)d_out;

    float* p = (float*)d_ws;
    float* xs = p;     p += (size_t)B_ * N_ * DIM_;
    float* xr = p;     p += (size_t)B_ * N_ * DIM_;
    float* kb = p;     p += (size_t)B_ * N_ * DIM_;
    float* vb = p;     p += (size_t)B_ * N_ * DIM_;
    float* qb = p;     p += (size_t)B_ * N_ * DIM_;
    float* lrb = p;    p += (size_t)BH_ * N_;
    float* gateb = p;  p += (size_t)BH_ * N_;
    float* pooled = p; p += (size_t)B_ * NC_ * DIM_;
    float* beta = p;   p += BH_ * NC_;
    float* alpha = p;  p += BH_ * NC_;
    float* sgb = p;    p += (size_t)BH_ * NC_ * DH_;

    __bf16* bp_ = (__bf16*)p;
    __bf16* xsb = bp_;  bp_ += (size_t)B_ * N_ * DIM_;
    __bf16* xrb = bp_;  bp_ += (size_t)B_ * N_ * DIM_;
    __bf16* retgb = bp_; bp_ += (size_t)B_ * N_ * DIM_;
    __bf16* w1b = bp_;  bp_ += DH_ * DHID_;
    __bf16* w1Tb = bp_; bp_ += DH_ * DHID_;
    __bf16* w2b = bp_;  bp_ += DH_ * DHID_;
    __bf16* w2Tb = bp_; bp_ += DH_ * DHID_;
    __bf16* WqT = bp_;  bp_ += DIM_ * DIM_;
    __bf16* WkT = bp_;  bp_ += DIM_ * DIM_;
    __bf16* WvT = bp_;  bp_ += DIM_ * DIM_;
    __bf16* WcT = bp_;  bp_ += DIM_ * DIM_;
    __bf16* sw1b = bp_; bp_ += (size_t)BH_ * NC_ * DH_ * DHID_;
    __bf16* sw2b = bp_; bp_ += (size_t)BH_ * NC_ * DH_ * DHID_;

    rms_kernel<<<B_ * N_, 256, 0, stream>>>(seq, g_store, g_retr, xs, xr, xsb, xrb);
    pooled_kernel<<<(B_ * NC_ * DIM_) / 256, 256, 0, stream>>>(xs, pooled);
    gates_kernel<<<(B_ * N_) / 4, 256, 0, stream>>>(xs, xr, Wa, ba, Wg, lrb, gateb);
    ba_kernel<<<1, 256, 0, stream>>>(pooled, Wm, Wd, bd, beta, alpha);
    prep_kernel<<<1024, 256, 0, stream>>>(w1, w2, Wq, Wk, Wv, Wc,
                                          w1b, w1Tb, w2b, w2Tb, WqT, WkT, WvT, WcT);
    gemm_bf<1><<<dim3(64, 8), 256, 0, stream>>>(xrb, WqT, qb);
    gemm_bf<1><<<dim3(64, 8), 256, 0, stream>>>(xsb, WkT, kb);
    gemm_bf<1><<<dim3(64, 8), 256, 0, stream>>>(xsb, WvT, vb);
    grad_kernel<<<BH_ * NC_, 512, 0, stream>>>(kb, vb, lrb, memg, w1b, w1Tb, w2b, w2Tb,
                                               sgb, sw1b, sw2b);
    scan_bf<<<(BH_ * 65536) / 256, 256, 0, stream>>>(sw1b, w1Tb, beta, alpha);
    scan_bf<<<(BH_ * 65536) / 256, 256, 0, stream>>>(sw2b, w2Tb, beta, alpha);
    scan_g<<<(BH_ * DH_) / 256, 256, 0, stream>>>(sgb, memg, beta, alpha);
    retrieve_kernel<<<BH_ * NC_, 256, 0, stream>>>(qb, gateb, sgb, sw1b, sw2b, retgb);
    gemm_bf<0><<<dim3(64, 8), 256, 0, stream>>>(retgb, WcT, out);
}

// Round 4
// 335.959 us; speedup vs baseline: 2.8945x; 1.1526x over previous
//
#include <hip/hip_runtime.h>
#include <hip/hip_bf16.h>

#define B_ 2
#define N_ 2048
#define DIM_ 512
#define H_ 4
#define DH_ 128
#define DHID_ 512
#define CH_ 64
#define NC_ 32
#define BH_ 8

typedef __bf16 bf16x8 __attribute__((ext_vector_type(8)));
typedef float f32x4 __attribute__((ext_vector_type(4)));

__device__ __forceinline__ f32x4 MFMA(bf16x8 a, bf16x8 b, f32x4 c) {
    return __builtin_amdgcn_mfma_f32_16x16x32_bf16(a, b, c, 0, 0, 0);
}
__device__ __forceinline__ bf16x8 ld8(const __bf16* p) { return *(const bf16x8*)p; }

__device__ __forceinline__ float sigmoidf_(float x) { return 1.0f / (1.0f + expf(-x)); }
__device__ __forceinline__ float gelu_f(float x) {
    return x * 0.5f * (1.0f + erff(x * 0.7071067811865476f));
}
__device__ __forceinline__ float gelu_g(float x) {
    float cdf = 0.5f * (1.0f + erff(x * 0.7071067811865476f));
    float pdf = 0.3989422804014327f * expf(-0.5f * x * x);
    return cdf + x * pdf;
}

// ---------------------------------------------------------------- rms norm + bf16 copies + fused lr/gate
__global__ __launch_bounds__(256) void rms_kernel(
    const float* __restrict__ seq, const float* __restrict__ gs,
    const float* __restrict__ gr, const float* __restrict__ Wa,
    const float* __restrict__ ba, const float* __restrict__ Wg,
    float* __restrict__ xs, float* __restrict__ xr,
    __bf16* __restrict__ xsb, __bf16* __restrict__ xrb,
    float* __restrict__ lrb, float* __restrict__ gateb)
{
    const int row = blockIdx.x;
    const int t = threadIdx.x;
    const int wave = t >> 6, lane = t & 63;
    const float* x = seq + (size_t)row * DIM_;
    float v0 = x[t], v1 = x[t + 256];
    float ss = v0 * v0 + v1 * v1;
#pragma unroll
    for (int off = 32; off; off >>= 1) ss += __shfl_xor(ss, off);
    __shared__ float red[4];
    __shared__ float red2[4][8];
    if (lane == 0) red[wave] = ss;
    __syncthreads();
    float tot = red[0] + red[1] + red[2] + red[3];
    float r = rsqrtf(tot * (1.0f / DIM_) + 1e-6f);
    size_t o = (size_t)row * DIM_;
    float a0 = v0 * r * gs[t], a1 = v1 * r * gs[t + 256];
    float b0 = v0 * r * gr[t], b1 = v1 * r * gr[t + 256];
    xs[o + t] = a0; xs[o + t + 256] = a1;
    xr[o + t] = b0; xr[o + t + 256] = b1;
    xsb[o + t] = (__bf16)a0; xsb[o + t + 256] = (__bf16)a1;
    xrb[o + t] = (__bf16)b0; xrb[o + t + 256] = (__bf16)b1;
    // fused per-token gates: lr = sigmoid(xs@Wa+ba), gate = sigmoid(xr@Wg)
    float pa[4], pg[4];
#pragma unroll
    for (int h = 0; h < 4; ++h) {
        pa[h] = a0 * Wa[t * 4 + h] + a1 * Wa[(t + 256) * 4 + h];
        pg[h] = b0 * Wg[t * 4 + h] + b1 * Wg[(t + 256) * 4 + h];
    }
#pragma unroll
    for (int h = 0; h < 4; ++h)
#pragma unroll
        for (int off = 32; off; off >>= 1) {
            pa[h] += __shfl_xor(pa[h], off);
            pg[h] += __shfl_xor(pg[h], off);
        }
    if (lane == 0) {
#pragma unroll
        for (int h = 0; h < 4; ++h) {
            red2[wave][h] = pa[h];
            red2[wave][4 + h] = pg[h];
        }
    }
    __syncthreads();
    if (t < 8) {
        float s = red2[0][t] + red2[1][t] + red2[2][t] + red2[3][t];
        int b = row >> 11, n = row & 2047;
        if (t < 4) lrb[(size_t)(b * 4 + t) * N_ + n] = sigmoidf_(s + ba[t]);
        else gateb[(size_t)(b * 4 + (t - 4)) * N_ + n] = sigmoidf_(s);
    }
}

// ---------------------------------------------------------------- pooled + beta/alpha fused
__global__ __launch_bounds__(256) void ba_kernel(
    const float* __restrict__ xs, const float* __restrict__ Wm,
    const float* __restrict__ Wd, const float* __restrict__ bd,
    float* __restrict__ beta, float* __restrict__ alpha)
{
    const int b = blockIdx.x >> 5, ci = blockIdx.x & 31;
    const int t = threadIdx.x;
    const int wave = t >> 6, lane = t & 63;
    const float* base = xs + ((size_t)b * N_ + ci * CH_) * DIM_;
    const int d0 = t * 2;
    float s0 = 0.f, s1 = 0.f;
#pragma unroll 8
    for (int r = 0; r < CH_; ++r) {
        s0 += base[(size_t)r * DIM_ + d0];
        s1 += base[(size_t)r * DIM_ + d0 + 1];
    }
    s0 *= (1.0f / CH_); s1 *= (1.0f / CH_);
    float pm[4], pd[4];
#pragma unroll
    for (int h = 0; h < 4; ++h) {
        pm[h] = s0 * Wm[d0 * 4 + h] + s1 * Wm[(d0 + 1) * 4 + h];
        pd[h] = s0 * Wd[d0 * 4 + h] + s1 * Wd[(d0 + 1) * 4 + h];
    }
#pragma unroll
    for (int h = 0; h < 4; ++h)
#pragma unroll
        for (int off = 32; off; off >>= 1) {
            pm[h] += __shfl_xor(pm[h], off);
            pd[h] += __shfl_xor(pd[h], off);
        }
    __shared__ float red2[4][8];
    if (lane == 0) {
#pragma unroll
        for (int h = 0; h < 4; ++h) {
            red2[wave][h] = pm[h];
            red2[wave][4 + h] = pd[h];
        }
    }
    __syncthreads();
    if (t < 4) {
        float sm = red2[0][t] + red2[1][t] + red2[2][t] + red2[3][t];
        float sd = red2[0][4 + t] + red2[1][4 + t] + red2[2][4 + t] + red2[3][4 + t];
        int bh = b * 4 + t;
        beta[bh * NC_ + ci] = sigmoidf_(sm);
        alpha[bh * NC_ + ci] = 1.0f - sigmoidf_(sd + bd[t]);
    }
}

// ---------------------------------------------------------------- weight prep: bf16 copies + transposes
__global__ __launch_bounds__(256) void prep_kernel(
    const float* __restrict__ w1, const float* __restrict__ w2,
    const float* __restrict__ Wq, const float* __restrict__ Wk,
    const float* __restrict__ Wv, const float* __restrict__ Wc,
    __bf16* __restrict__ w1b, __bf16* __restrict__ w1Tb,
    __bf16* __restrict__ w2b, __bf16* __restrict__ w2Tb,
    __bf16* __restrict__ WqT, __bf16* __restrict__ WkT,
    __bf16* __restrict__ WvT, __bf16* __restrict__ WcT)
{
    int idx = blockIdx.x * 256 + threadIdx.x;   // 262144
    if (idx < 65536) {
        w1b[idx] = (__bf16)w1[idx];                       // [d][j]
        int j = idx >> 7, d = idx & 127;
        w1Tb[idx] = (__bf16)w1[(size_t)d * DHID_ + j];    // [j][d]
        w2b[idx] = (__bf16)w2[idx];                       // [j][d]
        int d2 = idx >> 9, j2 = idx & 511;
        w2Tb[idx] = (__bf16)w2[(size_t)j2 * DH_ + d2];    // [d][j]
    }
    int n = idx >> 9, k = idx & 511;                      // WT[n][k] = W[k][n]
    WqT[idx] = (__bf16)Wq[(size_t)k * 512 + n];
    WkT[idx] = (__bf16)Wk[(size_t)k * 512 + n];
    WvT[idx] = (__bf16)Wv[(size_t)k * 512 + n];
    WcT[idx] = (__bf16)Wc[(size_t)k * 512 + n];
}

// ---------------------------------------------------------------- projections q/k/v: one launch, grid.z selects
__global__ __launch_bounds__(256, 4) void proj_kernel(
    const __bf16* __restrict__ xsb, const __bf16* __restrict__ xrb,
    const __bf16* __restrict__ WqT, const __bf16* __restrict__ WkT,
    const __bf16* __restrict__ WvT,
    float* __restrict__ qb, float* __restrict__ kb, float* __restrict__ vb)
{
    const int z = blockIdx.z;
    const __bf16* A = (z == 0) ? xrb : xsb;
    const __bf16* WT = (z == 0) ? WqT : (z == 1 ? WkT : WvT);
    float* out = (z == 0) ? qb : (z == 1 ? kb : vb);
    const int t = threadIdx.x;
    const int wave = t >> 6, lane = t & 63;
    const int lrow = lane & 15, lgrp = lane >> 4;
    const int c0 = blockIdx.x * 64 + wave * 16;
    const int col0 = blockIdx.y * 64;
    f32x4 acc[4];
#pragma unroll
    for (int i = 0; i < 4; ++i) acc[i] = (f32x4)0.f;
    const __bf16* ar = A + (size_t)(c0 + lrow) * 512;
#pragma unroll 4
    for (int k0 = 0; k0 < 512; k0 += 32) {
        bf16x8 av = ld8(ar + k0 + lgrp * 8);
#pragma unroll
        for (int ct = 0; ct < 4; ++ct) {
            bf16x8 bv = ld8(WT + (size_t)(col0 + ct * 16 + lrow) * 512 + k0 + lgrp * 8);
            acc[ct] = MFMA(av, bv, acc[ct]);
        }
    }
#pragma unroll
    for (int ct = 0; ct < 4; ++ct)
#pragma unroll
        for (int r = 0; r < 4; ++r) {
            int row = c0 + lgrp * 4 + r, col = col0 + ct * 16 + lrow;
            int b = row >> 11, n = row & 2047, h = col >> 7, d = col & 127;
            out[((((size_t)(b * H_ + h) * NC_ + (n >> 6)) * CH_) + (n & 63)) * DH_ + d] = acc[ct][r];
        }
}

// ---------------------------------------------------------------- final combine GEMM (row-major out)
__global__ __launch_bounds__(256, 4) void gemm_out(
    const __bf16* __restrict__ A, const __bf16* __restrict__ WT, float* __restrict__ out)
{
    const int t = threadIdx.x;
    const int wave = t >> 6, lane = t & 63;
    const int lrow = lane & 15, lgrp = lane >> 4;
    const int c0 = blockIdx.x * 64 + wave * 16;
    const int col0 = blockIdx.y * 64;
    f32x4 acc[4];
#pragma unroll
    for (int i = 0; i < 4; ++i) acc[i] = (f32x4)0.f;
    const __bf16* ar = A + (size_t)(c0 + lrow) * 512;
#pragma unroll 4
    for (int k0 = 0; k0 < 512; k0 += 32) {
        bf16x8 av = ld8(ar + k0 + lgrp * 8);
#pragma unroll
        for (int ct = 0; ct < 4; ++ct) {
            bf16x8 bv = ld8(WT + (size_t)(col0 + ct * 16 + lrow) * 512 + k0 + lgrp * 8);
            acc[ct] = MFMA(av, bv, acc[ct]);
        }
    }
#pragma unroll
    for (int ct = 0; ct < 4; ++ct)
#pragma unroll
        for (int r = 0; r < 4; ++r) {
            int row = c0 + lgrp * 4 + r, col = col0 + ct * 16 + lrow;
            out[(size_t)row * 512 + col] = acc[ct][r];
        }
}

// ---------------------------------------------------------------- per-chunk surprise gradients (MFMA, 16 waves)
__global__ __launch_bounds__(1024) void grad_kernel(
    const float* __restrict__ kbuf, const float* __restrict__ vbuf,
    const float* __restrict__ lrbuf, const float* __restrict__ memg,
    const __bf16* __restrict__ w1b, const __bf16* __restrict__ w1Tb,
    const __bf16* __restrict__ w2b, const __bf16* __restrict__ w2Tb,
    float* __restrict__ sg, __bf16* __restrict__ sw1, __bf16* __restrict__ sw2)
{
    const int blk = blockIdx.x;
    const int t = threadIdx.x;
    const int w = t >> 6, lane = t & 63;
    const int lrow = lane & 15, lgrp = lane >> 4;
    const int bh = blk >> 5, nc = blk & 31;
    const float* kc = kbuf + (size_t)blk * (CH_ * DH_);
    const float* vc = vbuf + (size_t)blk * (CH_ * DH_);
    const float* lrp = lrbuf + (size_t)bh * N_ + nc * CH_;
    __bf16* sw1_blk = sw1 + (size_t)blk * (DHID_ * DH_);
    __bf16* sw2_blk = sw2 + (size_t)blk * (DHID_ * DH_);

    __shared__ __bf16 h_s[64][136];
    __shared__ __bf16 e_s[64][136];
    __shared__ __bf16 a_s[64][136];
    __shared__ __bf16 dz_s[64][136];
    __shared__ __bf16 hT_s[128][72];
    __shared__ __bf16 eT_s[128][72];
    __shared__ __bf16 aT_s[128][72];
    __shared__ __bf16 dzT_s[128][72];
    __shared__ float r_s[64];
    __shared__ float lr_s[64];
    __shared__ float g_s[128];
    __shared__ float part_s[2][128];

    // ---- phase A: load k-chunk, rms, h = x*r*g ----
    if (t < 128) g_s[t] = memg[t];
    if (t < 64) lr_s[t] = lrp[t];
    {
        const int c = t >> 4, i8 = t & 15, d0 = i8 * 8;
        float xv[8];
        float ss = 0.f;
#pragma unroll
        for (int i = 0; i < 2; ++i) {
            float4 f = *(const float4*)(kc + (size_t)c * DH_ + d0 + i * 4);
            xv[i * 4 + 0] = f.x; xv[i * 4 + 1] = f.y; xv[i * 4 + 2] = f.z; xv[i * 4 + 3] = f.w;
            ss += f.x * f.x + f.y * f.y + f.z * f.z + f.w * f.w;
        }
        ss += __shfl_xor(ss, 1); ss += __shfl_xor(ss, 2);
        ss += __shfl_xor(ss, 4); ss += __shfl_xor(ss, 8);
        float r = rsqrtf(ss * (1.0f / DH_) + 1e-6f);
        if (i8 == 0) r_s[c] = r;
        __syncthreads();   // g_s visible
#pragma unroll
        for (int i = 0; i < 8; ++i)
            h_s[c][d0 + i] = (__bf16)(xv[i] * r * g_s[d0 + i]);
    }
    __syncthreads();
    {   // hT fill
        const int d = t >> 3, c0 = (t & 7) * 8;
#pragma unroll
        for (int i = 0; i < 8; ++i) hT_s[d][c0 + i] = h_s[c0 + i][d];
    }
    __syncthreads();

    // ---- pass 1: forward ---- wave -> (c-strip 16, d/j-quarter 32)
    const int cs = w & 3, dq = w >> 2;
    const int c0w = cs * 16, q0 = dq * 32;
    f32x4 yacc[2];
    yacc[0] = (f32x4)0.f; yacc[1] = (f32x4)0.f;

    for (int jt = 0; jt < 4; ++jt) {
        f32x4 zacc[2];
        zacc[0] = (f32x4)0.f; zacc[1] = (f32x4)0.f;
#pragma unroll
        for (int kt = 0; kt < 4; ++kt) {
            bf16x8 av = ld8(&h_s[c0w + lrow][kt * 32 + lgrp * 8]);
#pragma unroll
            for (int ct = 0; ct < 2; ++ct) {
                int j = jt * 128 + q0 + ct * 16 + lrow;
                bf16x8 bv = ld8(w1Tb + (size_t)j * 128 + kt * 32 + lgrp * 8);
                zacc[ct] = MFMA(av, bv, zacc[ct]);
            }
        }
#pragma unroll
        for (int ct = 0; ct < 2; ++ct)
#pragma unroll
            for (int r = 0; r < 4; ++r)
                a_s[c0w + lgrp * 4 + r][q0 + ct * 16 + lrow] = (__bf16)gelu_f(zacc[ct][r]);
        __syncthreads();
#pragma unroll
        for (int kt = 0; kt < 4; ++kt) {
            bf16x8 av = ld8(&a_s[c0w + lrow][kt * 32 + lgrp * 8]);
#pragma unroll
            for (int ct = 0; ct < 2; ++ct) {
                int d = q0 + ct * 16 + lrow;
                bf16x8 bv = ld8(w2Tb + (size_t)d * 512 + jt * 128 + kt * 32 + lgrp * 8);
                yacc[ct] = MFMA(av, bv, yacc[ct]);
            }
        }
        __syncthreads();
    }
    // e = lr*2/DH*(y + x - v)
#pragma unroll
    for (int ct = 0; ct < 2; ++ct)
#pragma unroll
        for (int r = 0; r < 4; ++r) {
            int c = c0w + lgrp * 4 + r, d = q0 + ct * 16 + lrow;
            float xvv = kc[(size_t)c * DH_ + d];
            float vvv = vc[(size_t)c * DH_ + d];
            float e = lr_s[c] * (2.0f / DH_) * (yacc[ct][r] + xvv - vvv);
            e_s[c][d] = (__bf16)e;
            eT_s[d][c] = (__bf16)e;
        }
    __syncthreads();

    // ---- pass 2: backward ---- wave -> (j/d-strip 16, c/d/j-half)
    const int js = w & 7, chh = w >> 3;
    f32x4 dhacc[2];
    dhacc[0] = (f32x4)0.f; dhacc[1] = (f32x4)0.f;

    for (int jt = 0; jt < 4; ++jt) {
        // zT[j-strip, c-half] = w1T @ hT ; daT = w2 @ eT
        f32x4 ztacc[2], dtacc[2];
        ztacc[0] = (f32x4)0.f; ztacc[1] = (f32x4)0.f;
        dtacc[0] = (f32x4)0.f; dtacc[1] = (f32x4)0.f;
#pragma unroll
        for (int kt = 0; kt < 4; ++kt) {
            bf16x8 avz = ld8(w1Tb + (size_t)(jt * 128 + js * 16 + lrow) * 128 + kt * 32 + lgrp * 8);
            bf16x8 avd = ld8(w2b  + (size_t)(jt * 128 + js * 16 + lrow) * 128 + kt * 32 + lgrp * 8);
#pragma unroll
            for (int ct = 0; ct < 2; ++ct) {
                bf16x8 bvh = ld8(&h_s[chh * 32 + ct * 16 + lrow][kt * 32 + lgrp * 8]);
                bf16x8 bve = ld8(&e_s[chh * 32 + ct * 16 + lrow][kt * 32 + lgrp * 8]);
                ztacc[ct] = MFMA(avz, bvh, ztacc[ct]);
                dtacc[ct] = MFMA(avd, bve, dtacc[ct]);
            }
        }
#pragma unroll
        for (int ct = 0; ct < 2; ++ct)
#pragma unroll
            for (int r = 0; r < 4; ++r) {
                int j = js * 16 + lgrp * 4 + r, c = chh * 32 + ct * 16 + lrow;
                float zt = ztacc[ct][r];
                aT_s[j][c] = (__bf16)gelu_f(zt);
                float dzt = dtacc[ct][r] * gelu_g(zt);
                dzT_s[j][c] = (__bf16)dzt;
                dz_s[c][j] = (__bf16)dzt;
            }
        __syncthreads();
        // dw1T[j-strip, d-half] = dzT @ h
        {
            f32x4 wacc[4];
#pragma unroll
            for (int i = 0; i < 4; ++i) wacc[i] = (f32x4)0.f;
#pragma unroll
            for (int kt = 0; kt < 2; ++kt) {
                bf16x8 av = ld8(&dzT_s[js * 16 + lrow][kt * 32 + lgrp * 8]);
#pragma unroll
                for (int ct = 0; ct < 4; ++ct) {
                    bf16x8 bv = ld8(&hT_s[chh * 64 + ct * 16 + lrow][kt * 32 + lgrp * 8]);
                    wacc[ct] = MFMA(av, bv, wacc[ct]);
                }
            }
#pragma unroll
            for (int ct = 0; ct < 4; ++ct)
#pragma unroll
                for (int r = 0; r < 4; ++r) {
                    int jg = jt * 128 + js * 16 + lgrp * 4 + r, d = chh * 64 + ct * 16 + lrow;
                    sw1_blk[(size_t)jg * 128 + d] = (__bf16)(-wacc[ct][r]);
                }
        }
        // dw2T[d-strip, j-half] = eT @ a
        {
            f32x4 wacc[4];
#pragma unroll
            for (int i = 0; i < 4; ++i) wacc[i] = (f32x4)0.f;
#pragma unroll
            for (int kt = 0; kt < 2; ++kt) {
                bf16x8 av = ld8(&eT_s[js * 16 + lrow][kt * 32 + lgrp * 8]);
#pragma unroll
                for (int ct = 0; ct < 4; ++ct) {
                    bf16x8 bv = ld8(&aT_s[chh * 64 + ct * 16 + lrow][kt * 32 + lgrp * 8]);
                    wacc[ct] = MFMA(av, bv, wacc[ct]);
                }
            }
#pragma unroll
            for (int ct = 0; ct < 4; ++ct)
#pragma unroll
                for (int r = 0; r < 4; ++r) {
                    int d = js * 16 + lgrp * 4 + r, jg = jt * 128 + chh * 64 + ct * 16 + lrow;
                    sw2_blk[(size_t)d * 512 + jg] = (__bf16)(-wacc[ct][r]);
                }
        }
        // dhT[d-strip, c-half] += w1 @ dz
#pragma unroll
        for (int kt = 0; kt < 4; ++kt) {
            bf16x8 av = ld8(w1b + (size_t)(js * 16 + lrow) * 512 + jt * 128 + kt * 32 + lgrp * 8);
#pragma unroll
            for (int ct = 0; ct < 2; ++ct) {
                bf16x8 bv = ld8(&dz_s[chh * 32 + ct * 16 + lrow][kt * 32 + lgrp * 8]);
                dhacc[ct] = MFMA(av, bv, dhacc[ct]);
            }
        }
        __syncthreads();
    }
    // dg[d] = sum_c dhT[d][c]*h[c][d] / g[d]
    {
        float s[4] = {0.f, 0.f, 0.f, 0.f};
#pragma unroll
        for (int ct = 0; ct < 2; ++ct)
#pragma unroll
            for (int r = 0; r < 4; ++r) {
                int d = js * 16 + lgrp * 4 + r, c = chh * 32 + ct * 16 + lrow;
                s[r] += dhacc[ct][r] * (float)hT_s[d][c];
            }
#pragma unroll
        for (int r = 0; r < 4; ++r) {
            s[r] += __shfl_xor(s[r], 1); s[r] += __shfl_xor(s[r], 2);
            s[r] += __shfl_xor(s[r], 4); s[r] += __shfl_xor(s[r], 8);
        }
        if (lrow == 0) {
#pragma unroll
            for (int r = 0; r < 4; ++r) part_s[chh][js * 16 + lgrp * 4 + r] = s[r];
        }
        __syncthreads();
        if (t < 128) sg[(size_t)blk * DH_ + t] = -(part_s[0][t] + part_s[1][t]) / g_s[t];
    }
}

// ---------------------------------------------------------------- all scans, one launch
__global__ __launch_bounds__(256) void scan_all(
    __bf16* __restrict__ sw1, const __bf16* __restrict__ w1T,
    __bf16* __restrict__ sw2, const __bf16* __restrict__ w2T,
    float* __restrict__ sgb, const float* __restrict__ memg,
    const float* __restrict__ beta, const float* __restrict__ alpha)
{
    const int bi = blockIdx.x, t = threadIdx.x;
    if (bi < 4096) {
        __bf16* buf = (bi < 2048) ? sw1 : sw2;
        const __bf16* init = (bi < 2048) ? w1T : w2T;
        int idx = (bi & 2047) * 256 + t;
        int bh = idx >> 16, el = idx & 65535;
        float wv = (float)init[el], m = 0.f;
        const float* bp = beta + bh * NC_;
        const float* ap = alpha + bh * NC_;
        __bf16* base = buf + ((size_t)bh * NC_) * 65536 + el;
        for (int ci = 0; ci < NC_; ++ci) {
            float s = (float)base[(size_t)ci * 65536];
            base[(size_t)ci * 65536] = (__bf16)wv;
            m = fmaf(bp[ci], m, s);
            wv = fmaf(ap[ci], wv, m);
        }
    } else {
        int idx = (bi - 4096) * 256 + t;   // < 1024
        int bh = idx >> 7, el = idx & 127;
        float wv = memg[el], m = 0.f;
        const float* bp = beta + bh * NC_;
        const float* ap = alpha + bh * NC_;
        float* base = sgb + ((size_t)bh * NC_) * 128 + el;
        for (int ci = 0; ci < NC_; ++ci) {
            float s = base[(size_t)ci * 128];
            base[(size_t)ci * 128] = wv;
            m = fmaf(bp[ci], m, s);
            wv = fmaf(ap[ci], wv, m);
        }
    }
}

// ---------------------------------------------------------------- retrieval (MFMA forward, 8 waves) + gate
__global__ __launch_bounds__(512, 4) void retrieve_kernel(
    const float* __restrict__ qbuf, const float* __restrict__ gatebuf,
    const float* __restrict__ sg, const __bf16* __restrict__ sw1,
    const __bf16* __restrict__ sw2, __bf16* __restrict__ retgb)
{
    const int blk = blockIdx.x;
    const int t = threadIdx.x;
    const int w = t >> 6, lane = t & 63;
    const int lrow = lane & 15, lgrp = lane >> 4;
    const int bh = blk >> 5, nc = blk & 31;
    const float* qc = qbuf + (size_t)blk * (CH_ * DH_);
    const __bf16* w1p = sw1 + (size_t)blk * (DHID_ * DH_);
    const __bf16* w2p = sw2 + (size_t)blk * (DHID_ * DH_);
    const float* gp = sg + (size_t)blk * DH_;

    __shared__ __bf16 h_s[64][136];
    __shared__ __bf16 a_s[64][136];
    __shared__ float g_s[128];

    if (t < 128) g_s[t] = gp[t];
    {
        const int c = t >> 3, dblk = t & 7, d0 = dblk * 16;
        float xv[16];
        float ss = 0.f;
#pragma unroll
        for (int i = 0; i < 4; ++i) {
            float4 f = *(const float4*)(qc + (size_t)c * DH_ + d0 + i * 4);
            xv[i * 4 + 0] = f.x; xv[i * 4 + 1] = f.y; xv[i * 4 + 2] = f.z; xv[i * 4 + 3] = f.w;
            ss += f.x * f.x + f.y * f.y + f.z * f.z + f.w * f.w;
        }
        ss += __shfl_xor(ss, 1); ss += __shfl_xor(ss, 2); ss += __shfl_xor(ss, 4);
        float r = rsqrtf(ss * (1.0f / DH_) + 1e-6f);
        __syncthreads();   // g_s visible
#pragma unroll
        for (int i = 0; i < 16; ++i)
            h_s[c][d0 + i] = (__bf16)(xv[i] * r * g_s[d0 + i]);
    }
    __syncthreads();

    const int cs = w & 3, dh2 = w >> 2;
    const int c0w = cs * 16, d0w = dh2 * 64;
    f32x4 yacc[4];
#pragma unroll
    for (int i = 0; i < 4; ++i) yacc[i] = (f32x4)0.f;

    for (int jt = 0; jt < 4; ++jt) {
        f32x4 zacc[4];
#pragma unroll
        for (int i = 0; i < 4; ++i) zacc[i] = (f32x4)0.f;
#pragma unroll
        for (int kt = 0; kt < 4; ++kt) {
            bf16x8 av = ld8(&h_s[c0w + lrow][kt * 32 + lgrp * 8]);
#pragma unroll
            for (int ct = 0; ct < 4; ++ct) {
                int j = jt * 128 + d0w + ct * 16 + lrow;
                bf16x8 bv = ld8(w1p + (size_t)j * 128 + kt * 32 + lgrp * 8);
                zacc[ct] = MFMA(av, bv, zacc[ct]);
            }
        }
#pragma unroll
        for (int ct = 0; ct < 4; ++ct)
#pragma unroll
            for (int r = 0; r < 4; ++r)
                a_s[c0w + lgrp * 4 + r][d0w + ct * 16 + lrow] = (__bf16)gelu_f(zacc[ct][r]);
        __syncthreads();
#pragma unroll
        for (int kt = 0; kt < 4; ++kt) {
            bf16x8 av = ld8(&a_s[c0w + lrow][kt * 32 + lgrp * 8]);
#pragma unroll
            for (int ct = 0; ct < 4; ++ct) {
                int d = d0w + ct * 16 + lrow;
                bf16x8 bv = ld8(w2p + (size_t)d * 512 + jt * 128 + kt * 32 + lgrp * 8);
                yacc[ct] = MFMA(av, bv, yacc[ct]);
            }
        }
        __syncthreads();
    }
    const int b = bh >> 2, hh = bh & 3;
#pragma unroll
    for (int ct = 0; ct < 4; ++ct)
#pragma unroll
        for (int r = 0; r < 4; ++r) {
            int c = c0w + lgrp * 4 + r, d = d0w + ct * 16 + lrow;
            int n = nc * CH_ + c;
            float q = qc[(size_t)c * DH_ + d];
            float gv = gatebuf[(size_t)bh * N_ + n];
            retgb[((size_t)(b * N_ + n)) * 512 + hh * 128 + d] = (__bf16)((yacc[ct][r] + q) * gv);
        }
}

// ---------------------------------------------------------------- launch
extern "C" void kernel_launch(void* const* d_in, const int* in_sizes, int n_in,
                              void* d_out, int out_size, void* d_ws, size_t ws_size,
                              hipStream_t stream) {
    const float* seq     = (const float*)d_in[0];
    const float* g_store = (const float*)d_in[1];
    const float* g_retr  = (const float*)d_in[2];
    const float* Wq = (const float*)d_in[3];
    const float* Wk = (const float*)d_in[4];
    const float* Wv = (const float*)d_in[5];
    const float* Wa = (const float*)d_in[6];
    const float* ba = (const float*)d_in[7];
    const float* Wm = (const float*)d_in[8];
    const float* Wd = (const float*)d_in[9];
    const float* bd = (const float*)d_in[10];
    const float* Wg = (const float*)d_in[11];
    const float* Wc = (const float*)d_in[12];
    const float* memg = (const float*)d_in[13];
    const float* w1 = (const float*)d_in[14];
    const float* w2 = (const float*)d_in[15];
    float* out = (float*)d_out;

    float* p = (float*)d_ws;
    float* xs = p;     p += (size_t)B_ * N_ * DIM_;
    float* xr = p;     p += (size_t)B_ * N_ * DIM_;
    float* kb = p;     p += (size_t)B_ * N_ * DIM_;
    float* vb = p;     p += (size_t)B_ * N_ * DIM_;
    float* qb = p;     p += (size_t)B_ * N_ * DIM_;
    float* lrb = p;    p += (size_t)BH_ * N_;
    float* gateb = p;  p += (size_t)BH_ * N_;
    float* beta = p;   p += BH_ * NC_;
    float* alpha = p;  p += BH_ * NC_;
    float* sgb = p;    p += (size_t)BH_ * NC_ * DH_;

    __bf16* bp_ = (__bf16*)p;
    __bf16* xsb = bp_;  bp_ += (size_t)B_ * N_ * DIM_;
    __bf16* xrb = bp_;  bp_ += (size_t)B_ * N_ * DIM_;
    __bf16* retgb = bp_; bp_ += (size_t)B_ * N_ * DIM_;
    __bf16* w1b = bp_;  bp_ += DH_ * DHID_;
    __bf16* w1Tb = bp_; bp_ += DH_ * DHID_;
    __bf16* w2b = bp_;  bp_ += DH_ * DHID_;
    __bf16* w2Tb = bp_; bp_ += DH_ * DHID_;
    __bf16* WqT = bp_;  bp_ += DIM_ * DIM_;
    __bf16* WkT = bp_;  bp_ += DIM_ * DIM_;
    __bf16* WvT = bp_;  bp_ += DIM_ * DIM_;
    __bf16* WcT = bp_;  bp_ += DIM_ * DIM_;
    __bf16* sw1b = bp_; bp_ += (size_t)BH_ * NC_ * DH_ * DHID_;
    __bf16* sw2b = bp_; bp_ += (size_t)BH_ * NC_ * DH_ * DHID_;

    rms_kernel<<<B_ * N_, 256, 0, stream>>>(seq, g_store, g_retr, Wa, ba, Wg,
                                            xs, xr, xsb, xrb, lrb, gateb);
    ba_kernel<<<B_ * NC_, 256, 0, stream>>>(xs, Wm, Wd, bd, beta, alpha);
    prep_kernel<<<1024, 256, 0, stream>>>(w1, w2, Wq, Wk, Wv, Wc,
                                          w1b, w1Tb, w2b, w2Tb, WqT, WkT, WvT, WcT);
    proj_kernel<<<dim3(64, 8, 3), 256, 0, stream>>>(xsb, xrb, WqT, WkT, WvT, qb, kb, vb);
    grad_kernel<<<BH_ * NC_, 1024, 0, stream>>>(kb, vb, lrb, memg, w1b, w1Tb, w2b, w2Tb,
                                                sgb, sw1b, sw2b);
    scan_all<<<4100, 256, 0, stream>>>(sw1b, w1Tb, sw2b, w2Tb, sgb, memg, beta, alpha);
    retrieve_kernel<<<BH_ * NC_, 512, 0, stream>>>(qb, gateb, sgb, sw1b, sw2b, retgb);
    gemm_out<<<dim3(64, 8), 256, 0, stream>>>(retgb, WcT, out);
}

// Round 5
// 315.302 us; speedup vs baseline: 3.0841x; 1.0655x over previous
//
#include <hip/hip_runtime.h>
#include <hip/hip_bf16.h>

#define B_ 2
#define N_ 2048
#define DIM_ 512
#define H_ 4
#define DH_ 128
#define DHID_ 512
#define CH_ 64
#define NC_ 32
#define BH_ 8

typedef __bf16 bf16x8 __attribute__((ext_vector_type(8)));
typedef float f32x4 __attribute__((ext_vector_type(4)));

__device__ __forceinline__ f32x4 MFMA(bf16x8 a, bf16x8 b, f32x4 c) {
    return __builtin_amdgcn_mfma_f32_16x16x32_bf16(a, b, c, 0, 0, 0);
}
__device__ __forceinline__ bf16x8 ld8(const __bf16* p) { return *(const bf16x8*)p; }

__device__ __forceinline__ float sigmoidf_(float x) { return 1.0f / (1.0f + expf(-x)); }

// fast tanh-form GELU: max |err| vs exact-erf GELU ~1e-3 (absmax headroom 0.31)
__device__ __forceinline__ float gelu_f(float x) {
    float x2 = x * x;
    float u = x * fmaf(0.0713548163f, x2, 1.5957691216f);   // 2*0.79788456*(x+0.044715x^3)
    float E = __expf(u);
    float r = __builtin_amdgcn_rcpf(E + 1.0f);
    return x * (1.0f - r);                                   // x*0.5*(1+tanh)
}
__device__ __forceinline__ void gelu_fg(float x, float& f, float& g) {
    float x2 = x * x;
    float u = x * fmaf(0.0713548163f, x2, 1.5957691216f);
    float E = __expf(u);
    float r = __builtin_amdgcn_rcpf(E + 1.0f);
    float omr = 1.0f - r;            // 0.5*(1+tanh)
    f = x * omr;
    float th = 1.0f - 2.0f * r;
    float ap = fmaf(0.1070322244f, x2, 0.7978845608f);       // d(inner)/dx
    g = fmaf(0.5f * x * (1.0f - th * th), ap, omr);
}

// ---------------------------------------------------------------- rms norm + bf16 copies + fused lr/gate
__global__ __launch_bounds__(256) void rms_kernel(
    const float* __restrict__ seq, const float* __restrict__ gs,
    const float* __restrict__ gr, const float* __restrict__ Wa,
    const float* __restrict__ ba, const float* __restrict__ Wg,
    float* __restrict__ xs,
    __bf16* __restrict__ xsb, __bf16* __restrict__ xrb,
    float* __restrict__ lrb, float* __restrict__ gateb)
{
    const int row = blockIdx.x;
    const int t = threadIdx.x;
    const int wave = t >> 6, lane = t & 63;
    const float* x = seq + (size_t)row * DIM_;
    float v0 = x[t], v1 = x[t + 256];
    float ss = v0 * v0 + v1 * v1;
#pragma unroll
    for (int off = 32; off; off >>= 1) ss += __shfl_xor(ss, off);
    __shared__ float red[4];
    __shared__ float red2[4][8];
    if (lane == 0) red[wave] = ss;
    __syncthreads();
    float tot = red[0] + red[1] + red[2] + red[3];
    float r = rsqrtf(tot * (1.0f / DIM_) + 1e-6f);
    size_t o = (size_t)row * DIM_;
    float a0 = v0 * r * gs[t], a1 = v1 * r * gs[t + 256];
    float b0 = v0 * r * gr[t], b1 = v1 * r * gr[t + 256];
    xs[o + t] = a0; xs[o + t + 256] = a1;
    xsb[o + t] = (__bf16)a0; xsb[o + t + 256] = (__bf16)a1;
    xrb[o + t] = (__bf16)b0; xrb[o + t + 256] = (__bf16)b1;
    float pa[4], pg[4];
#pragma unroll
    for (int h = 0; h < 4; ++h) {
        pa[h] = a0 * Wa[t * 4 + h] + a1 * Wa[(t + 256) * 4 + h];
        pg[h] = b0 * Wg[t * 4 + h] + b1 * Wg[(t + 256) * 4 + h];
    }
#pragma unroll
    for (int h = 0; h < 4; ++h)
#pragma unroll
        for (int off = 32; off; off >>= 1) {
            pa[h] += __shfl_xor(pa[h], off);
            pg[h] += __shfl_xor(pg[h], off);
        }
    if (lane == 0) {
#pragma unroll
        for (int h = 0; h < 4; ++h) {
            red2[wave][h] = pa[h];
            red2[wave][4 + h] = pg[h];
        }
    }
    __syncthreads();
    if (t < 8) {
        float s = red2[0][t] + red2[1][t] + red2[2][t] + red2[3][t];
        int b = row >> 11, n = row & 2047;
        if (t < 4) lrb[(size_t)(b * 4 + t) * N_ + n] = sigmoidf_(s + ba[t]);
        else gateb[(size_t)(b * 4 + (t - 4)) * N_ + n] = sigmoidf_(s);
    }
}

// ---------------------------------------------------------------- pooled + beta/alpha fused
__global__ __launch_bounds__(256) void ba_kernel(
    const float* __restrict__ xs, const float* __restrict__ Wm,
    const float* __restrict__ Wd, const float* __restrict__ bd,
    float* __restrict__ beta, float* __restrict__ alpha)
{
    const int b = blockIdx.x >> 5, ci = blockIdx.x & 31;
    const int t = threadIdx.x;
    const int wave = t >> 6, lane = t & 63;
    const float* base = xs + ((size_t)b * N_ + ci * CH_) * DIM_;
    const int d0 = t * 2;
    float s0 = 0.f, s1 = 0.f;
#pragma unroll 8
    for (int r = 0; r < CH_; ++r) {
        s0 += base[(size_t)r * DIM_ + d0];
        s1 += base[(size_t)r * DIM_ + d0 + 1];
    }
    s0 *= (1.0f / CH_); s1 *= (1.0f / CH_);
    float pm[4], pd[4];
#pragma unroll
    for (int h = 0; h < 4; ++h) {
        pm[h] = s0 * Wm[d0 * 4 + h] + s1 * Wm[(d0 + 1) * 4 + h];
        pd[h] = s0 * Wd[d0 * 4 + h] + s1 * Wd[(d0 + 1) * 4 + h];
    }
#pragma unroll
    for (int h = 0; h < 4; ++h)
#pragma unroll
        for (int off = 32; off; off >>= 1) {
            pm[h] += __shfl_xor(pm[h], off);
            pd[h] += __shfl_xor(pd[h], off);
        }
    __shared__ float red2[4][8];
    if (lane == 0) {
#pragma unroll
        for (int h = 0; h < 4; ++h) {
            red2[wave][h] = pm[h];
            red2[wave][4 + h] = pd[h];
        }
    }
    __syncthreads();
    if (t < 4) {
        float sm = red2[0][t] + red2[1][t] + red2[2][t] + red2[3][t];
        float sd = red2[0][4 + t] + red2[1][4 + t] + red2[2][4 + t] + red2[3][4 + t];
        int bh = b * 4 + t;
        beta[bh * NC_ + ci] = sigmoidf_(sm);
        alpha[bh * NC_ + ci] = 1.0f - sigmoidf_(sd + bd[t]);
    }
}

// ---------------------------------------------------------------- weight prep: bf16 copies + transposes
__global__ __launch_bounds__(256) void prep_kernel(
    const float* __restrict__ w1, const float* __restrict__ w2,
    const float* __restrict__ Wq, const float* __restrict__ Wk,
    const float* __restrict__ Wv, const float* __restrict__ Wc,
    __bf16* __restrict__ w1b, __bf16* __restrict__ w1Tb,
    __bf16* __restrict__ w2b, __bf16* __restrict__ w2Tb,
    __bf16* __restrict__ WqT, __bf16* __restrict__ WkT,
    __bf16* __restrict__ WvT, __bf16* __restrict__ WcT)
{
    int idx = blockIdx.x * 256 + threadIdx.x;   // 262144
    if (idx < 65536) {
        w1b[idx] = (__bf16)w1[idx];                       // [d][j]
        int j = idx >> 7, d = idx & 127;
        w1Tb[idx] = (__bf16)w1[(size_t)d * DHID_ + j];    // [j][d]
        w2b[idx] = (__bf16)w2[idx];                       // [j][d]
        int d2 = idx >> 9, j2 = idx & 511;
        w2Tb[idx] = (__bf16)w2[(size_t)j2 * DH_ + d2];    // [d][j]
    }
    int n = idx >> 9, k = idx & 511;                      // WT[n][k] = W[k][n]
    WqT[idx] = (__bf16)Wq[(size_t)k * 512 + n];
    WkT[idx] = (__bf16)Wk[(size_t)k * 512 + n];
    WvT[idx] = (__bf16)Wv[(size_t)k * 512 + n];
    WcT[idx] = (__bf16)Wc[(size_t)k * 512 + n];
}

// ---------------------------------------------------------------- projections q/k/v: one launch, grid.z selects
__global__ __launch_bounds__(256, 4) void proj_kernel(
    const __bf16* __restrict__ xsb, const __bf16* __restrict__ xrb,
    const __bf16* __restrict__ WqT, const __bf16* __restrict__ WkT,
    const __bf16* __restrict__ WvT,
    float* __restrict__ qb, float* __restrict__ kb, float* __restrict__ vb)
{
    const int z = blockIdx.z;
    const __bf16* A = (z == 0) ? xrb : xsb;
    const __bf16* WT = (z == 0) ? WqT : (z == 1 ? WkT : WvT);
    float* out = (z == 0) ? qb : (z == 1 ? kb : vb);
    const int t = threadIdx.x;
    const int wave = t >> 6, lane = t & 63;
    const int lrow = lane & 15, lgrp = lane >> 4;
    const int c0 = blockIdx.x * 64 + wave * 16;
    const int col0 = blockIdx.y * 64;
    f32x4 acc[4];
#pragma unroll
    for (int i = 0; i < 4; ++i) acc[i] = (f32x4)0.f;
    const __bf16* ar = A + (size_t)(c0 + lrow) * 512;
#pragma unroll 4
    for (int k0 = 0; k0 < 512; k0 += 32) {
        bf16x8 av = ld8(ar + k0 + lgrp * 8);
#pragma unroll
        for (int ct = 0; ct < 4; ++ct) {
            bf16x8 bv = ld8(WT + (size_t)(col0 + ct * 16 + lrow) * 512 + k0 + lgrp * 8);
            acc[ct] = MFMA(av, bv, acc[ct]);
        }
    }
#pragma unroll
    for (int ct = 0; ct < 4; ++ct)
#pragma unroll
        for (int r = 0; r < 4; ++r) {
            int row = c0 + lgrp * 4 + r, col = col0 + ct * 16 + lrow;
            int b = row >> 11, n = row & 2047, h = col >> 7, d = col & 127;
            out[((((size_t)(b * H_ + h) * NC_ + (n >> 6)) * CH_) + (n & 63)) * DH_ + d] = acc[ct][r];
        }
}

// ---------------------------------------------------------------- final combine GEMM (row-major out)
__global__ __launch_bounds__(256, 4) void gemm_out(
    const __bf16* __restrict__ A, const __bf16* __restrict__ WT, float* __restrict__ out)
{
    const int t = threadIdx.x;
    const int wave = t >> 6, lane = t & 63;
    const int lrow = lane & 15, lgrp = lane >> 4;
    const int c0 = blockIdx.x * 64 + wave * 16;
    const int col0 = blockIdx.y * 64;
    f32x4 acc[4];
#pragma unroll
    for (int i = 0; i < 4; ++i) acc[i] = (f32x4)0.f;
    const __bf16* ar = A + (size_t)(c0 + lrow) * 512;
#pragma unroll 4
    for (int k0 = 0; k0 < 512; k0 += 32) {
        bf16x8 av = ld8(ar + k0 + lgrp * 8);
#pragma unroll
        for (int ct = 0; ct < 4; ++ct) {
            bf16x8 bv = ld8(WT + (size_t)(col0 + ct * 16 + lrow) * 512 + k0 + lgrp * 8);
            acc[ct] = MFMA(av, bv, acc[ct]);
        }
    }
#pragma unroll
    for (int ct = 0; ct < 4; ++ct)
#pragma unroll
        for (int r = 0; r < 4; ++r) {
            int row = c0 + lgrp * 4 + r, col = col0 + ct * 16 + lrow;
            out[(size_t)row * 512 + col] = acc[ct][r];
        }
}

// ---------------------------------------------------------------- per-chunk surprise gradients (MFMA, 16 waves)
// fast gelu + register weight-prefetch across barriers (T14 issue-early/use-late)
__global__ __launch_bounds__(1024) void grad_kernel(
    const float* __restrict__ kbuf, const float* __restrict__ vbuf,
    const float* __restrict__ lrbuf, const float* __restrict__ memg,
    const __bf16* __restrict__ w1b, const __bf16* __restrict__ w1Tb,
    const __bf16* __restrict__ w2b, const __bf16* __restrict__ w2Tb,
    float* __restrict__ sg, __bf16* __restrict__ sw1, __bf16* __restrict__ sw2)
{
    const int blk = blockIdx.x;
    const int t = threadIdx.x;
    const int w = t >> 6, lane = t & 63;
    const int lrow = lane & 15, lgrp = lane >> 4;
    const int bh = blk >> 5, nc = blk & 31;
    const float* kc = kbuf + (size_t)blk * (CH_ * DH_);
    const float* vc = vbuf + (size_t)blk * (CH_ * DH_);
    const float* lrp = lrbuf + (size_t)bh * N_ + nc * CH_;
    __bf16* sw1_blk = sw1 + (size_t)blk * (DHID_ * DH_);
    __bf16* sw2_blk = sw2 + (size_t)blk * (DHID_ * DH_);

    __shared__ __bf16 h_s[64][136];
    __shared__ __bf16 e_s[64][136];
    __shared__ __bf16 a_s[64][136];
    __shared__ __bf16 dz_s[64][136];
    __shared__ __bf16 hT_s[128][72];
    __shared__ __bf16 eT_s[128][72];
    __shared__ __bf16 aT_s[128][72];
    __shared__ __bf16 dzT_s[128][72];
    __shared__ float r_s[64];
    __shared__ float lr_s[64];
    __shared__ float g_s[128];
    __shared__ float part_s[2][128];

    // ---- phase A: load k-chunk, rms, h = x*r*g ----
    if (t < 128) g_s[t] = memg[t];
    if (t < 64) lr_s[t] = lrp[t];
    {
        const int c = t >> 4, i8 = t & 15, d0 = i8 * 8;
        float xv[8];
        float ss = 0.f;
#pragma unroll
        for (int i = 0; i < 2; ++i) {
            float4 f = *(const float4*)(kc + (size_t)c * DH_ + d0 + i * 4);
            xv[i * 4 + 0] = f.x; xv[i * 4 + 1] = f.y; xv[i * 4 + 2] = f.z; xv[i * 4 + 3] = f.w;
            ss += f.x * f.x + f.y * f.y + f.z * f.z + f.w * f.w;
        }
        ss += __shfl_xor(ss, 1); ss += __shfl_xor(ss, 2);
        ss += __shfl_xor(ss, 4); ss += __shfl_xor(ss, 8);
        float r = rsqrtf(ss * (1.0f / DH_) + 1e-6f);
        if (i8 == 0) r_s[c] = r;
        __syncthreads();   // g_s visible
#pragma unroll
        for (int i = 0; i < 8; ++i)
            h_s[c][d0 + i] = (__bf16)(xv[i] * r * g_s[d0 + i]);
    }
    __syncthreads();
    {   // hT fill
        const int d = t >> 3, c0 = (t & 7) * 8;
#pragma unroll
        for (int i = 0; i < 8; ++i) hT_s[d][c0 + i] = h_s[c0 + i][d];
    }
    __syncthreads();

    // ---- pass 1: forward ---- wave -> (c-strip 16, d/j-quarter 32)
    const int cs = w & 3, dq = w >> 2;
    const int c0w = cs * 16, q0 = dq * 32;
    f32x4 yacc[2];
    yacc[0] = (f32x4)0.f; yacc[1] = (f32x4)0.f;

    bf16x8 w1r[8], w2r[8];
#pragma unroll
    for (int kt = 0; kt < 4; ++kt)
#pragma unroll
        for (int ct = 0; ct < 2; ++ct)
            w1r[kt * 2 + ct] = ld8(w1Tb + (size_t)(q0 + ct * 16 + lrow) * 128 + kt * 32 + lgrp * 8);

    for (int jt = 0; jt < 4; ++jt) {
        f32x4 zacc[2];
        zacc[0] = (f32x4)0.f; zacc[1] = (f32x4)0.f;
#pragma unroll
        for (int kt = 0; kt < 4; ++kt) {
            bf16x8 av = ld8(&h_s[c0w + lrow][kt * 32 + lgrp * 8]);
            zacc[0] = MFMA(av, w1r[kt * 2 + 0], zacc[0]);
            zacc[1] = MFMA(av, w1r[kt * 2 + 1], zacc[1]);
        }
        // prefetch this jt's w2 columns (used after barrier)
#pragma unroll
        for (int kt = 0; kt < 4; ++kt)
#pragma unroll
            for (int ct = 0; ct < 2; ++ct)
                w2r[kt * 2 + ct] = ld8(w2Tb + (size_t)(q0 + ct * 16 + lrow) * 512 + jt * 128 + kt * 32 + lgrp * 8);
#pragma unroll
        for (int ct = 0; ct < 2; ++ct)
#pragma unroll
            for (int r = 0; r < 4; ++r)
                a_s[c0w + lgrp * 4 + r][q0 + ct * 16 + lrow] = (__bf16)gelu_f(zacc[ct][r]);
        __syncthreads();
#pragma unroll
        for (int kt = 0; kt < 4; ++kt) {
            bf16x8 av = ld8(&a_s[c0w + lrow][kt * 32 + lgrp * 8]);
            yacc[0] = MFMA(av, w2r[kt * 2 + 0], yacc[0]);
            yacc[1] = MFMA(av, w2r[kt * 2 + 1], yacc[1]);
        }
        // prefetch next jt's w1 columns (used after barrier)
        if (jt < 3) {
#pragma unroll
            for (int kt = 0; kt < 4; ++kt)
#pragma unroll
                for (int ct = 0; ct < 2; ++ct)
                    w1r[kt * 2 + ct] = ld8(w1Tb + (size_t)((jt + 1) * 128 + q0 + ct * 16 + lrow) * 128 + kt * 32 + lgrp * 8);
        }
        __syncthreads();
    }
    // e = lr*2/DH*(y + x - v)
#pragma unroll
    for (int ct = 0; ct < 2; ++ct)
#pragma unroll
        for (int r = 0; r < 4; ++r) {
            int c = c0w + lgrp * 4 + r, d = q0 + ct * 16 + lrow;
            float xvv = kc[(size_t)c * DH_ + d];
            float vvv = vc[(size_t)c * DH_ + d];
            float e = lr_s[c] * (2.0f / DH_) * (yacc[ct][r] + xvv - vvv);
            e_s[c][d] = (__bf16)e;
            eT_s[d][c] = (__bf16)e;
        }
    __syncthreads();

    // ---- pass 2: backward ---- wave -> (j/d-strip 16, c/d/j-half)
    const int js = w & 7, chh = w >> 3;
    f32x4 dhacc[2];
    dhacc[0] = (f32x4)0.f; dhacc[1] = (f32x4)0.f;

    bf16x8 azr[4], adr[4], w1br[4];
#pragma unroll
    for (int kt = 0; kt < 4; ++kt) {
        azr[kt] = ld8(w1Tb + (size_t)(js * 16 + lrow) * 128 + kt * 32 + lgrp * 8);
        adr[kt] = ld8(w2b + (size_t)(js * 16 + lrow) * 128 + kt * 32 + lgrp * 8);
    }

    for (int jt = 0; jt < 4; ++jt) {
        // zT[j-strip, c-half] = w1T @ hT ; daT = w2 @ eT
        f32x4 ztacc[2], dtacc[2];
        ztacc[0] = (f32x4)0.f; ztacc[1] = (f32x4)0.f;
        dtacc[0] = (f32x4)0.f; dtacc[1] = (f32x4)0.f;
#pragma unroll
        for (int kt = 0; kt < 4; ++kt) {
#pragma unroll
            for (int ct = 0; ct < 2; ++ct) {
                bf16x8 bvh = ld8(&h_s[chh * 32 + ct * 16 + lrow][kt * 32 + lgrp * 8]);
                bf16x8 bve = ld8(&e_s[chh * 32 + ct * 16 + lrow][kt * 32 + lgrp * 8]);
                ztacc[ct] = MFMA(azr[kt], bvh, ztacc[ct]);
                dtacc[ct] = MFMA(adr[kt], bve, dtacc[ct]);
            }
        }
        // prefetch this jt's w1b rows for dh (used after barrier)
#pragma unroll
        for (int kt = 0; kt < 4; ++kt)
            w1br[kt] = ld8(w1b + (size_t)(js * 16 + lrow) * 512 + jt * 128 + kt * 32 + lgrp * 8);
#pragma unroll
        for (int ct = 0; ct < 2; ++ct)
#pragma unroll
            for (int r = 0; r < 4; ++r) {
                int j = js * 16 + lgrp * 4 + r, c = chh * 32 + ct * 16 + lrow;
                float zt = ztacc[ct][r];
                float gf, gg;
                gelu_fg(zt, gf, gg);
                aT_s[j][c] = (__bf16)gf;
                float dzt = dtacc[ct][r] * gg;
                dzT_s[j][c] = (__bf16)dzt;
                dz_s[c][j] = (__bf16)dzt;
            }
        __syncthreads();
        // dw1T[j-strip, d-half] = dzT @ h
        {
            f32x4 wacc[4];
#pragma unroll
            for (int i = 0; i < 4; ++i) wacc[i] = (f32x4)0.f;
#pragma unroll
            for (int kt = 0; kt < 2; ++kt) {
                bf16x8 av = ld8(&dzT_s[js * 16 + lrow][kt * 32 + lgrp * 8]);
#pragma unroll
                for (int ct = 0; ct < 4; ++ct) {
                    bf16x8 bv = ld8(&hT_s[chh * 64 + ct * 16 + lrow][kt * 32 + lgrp * 8]);
                    wacc[ct] = MFMA(av, bv, wacc[ct]);
                }
            }
#pragma unroll
            for (int ct = 0; ct < 4; ++ct)
#pragma unroll
                for (int r = 0; r < 4; ++r) {
                    int jg = jt * 128 + js * 16 + lgrp * 4 + r, d = chh * 64 + ct * 16 + lrow;
                    sw1_blk[(size_t)jg * 128 + d] = (__bf16)(-wacc[ct][r]);
                }
        }
        // dw2T[d-strip, j-half] = eT @ a
        {
            f32x4 wacc[4];
#pragma unroll
            for (int i = 0; i < 4; ++i) wacc[i] = (f32x4)0.f;
#pragma unroll
            for (int kt = 0; kt < 2; ++kt) {
                bf16x8 av = ld8(&eT_s[js * 16 + lrow][kt * 32 + lgrp * 8]);
#pragma unroll
                for (int ct = 0; ct < 4; ++ct) {
                    bf16x8 bv = ld8(&aT_s[chh * 64 + ct * 16 + lrow][kt * 32 + lgrp * 8]);
                    wacc[ct] = MFMA(av, bv, wacc[ct]);
                }
            }
#pragma unroll
            for (int ct = 0; ct < 4; ++ct)
#pragma unroll
                for (int r = 0; r < 4; ++r) {
                    int d = js * 16 + lgrp * 4 + r, jg = jt * 128 + chh * 64 + ct * 16 + lrow;
                    sw2_blk[(size_t)d * 512 + jg] = (__bf16)(-wacc[ct][r]);
                }
        }
        // dhT[d-strip, c-half] += w1 @ dz
#pragma unroll
        for (int kt = 0; kt < 4; ++kt) {
#pragma unroll
            for (int ct = 0; ct < 2; ++ct) {
                bf16x8 bv = ld8(&dz_s[chh * 32 + ct * 16 + lrow][kt * 32 + lgrp * 8]);
                dhacc[ct] = MFMA(w1br[kt], bv, dhacc[ct]);
            }
        }
        // prefetch next jt's azr/adr (used after barrier)
        if (jt < 3) {
#pragma unroll
            for (int kt = 0; kt < 4; ++kt) {
                azr[kt] = ld8(w1Tb + (size_t)((jt + 1) * 128 + js * 16 + lrow) * 128 + kt * 32 + lgrp * 8);
                adr[kt] = ld8(w2b + (size_t)((jt + 1) * 128 + js * 16 + lrow) * 128 + kt * 32 + lgrp * 8);
            }
        }
        __syncthreads();
    }
    // dg[d] = sum_c dhT[d][c]*h[c][d] / g[d]
    {
        float s[4] = {0.f, 0.f, 0.f, 0.f};
#pragma unroll
        for (int ct = 0; ct < 2; ++ct)
#pragma unroll
            for (int r = 0; r < 4; ++r) {
                int d = js * 16 + lgrp * 4 + r, c = chh * 32 + ct * 16 + lrow;
                s[r] += dhacc[ct][r] * (float)hT_s[d][c];
            }
#pragma unroll
        for (int r = 0; r < 4; ++r) {
            s[r] += __shfl_xor(s[r], 1); s[r] += __shfl_xor(s[r], 2);
            s[r] += __shfl_xor(s[r], 4); s[r] += __shfl_xor(s[r], 8);
        }
        if (lrow == 0) {
#pragma unroll
            for (int r = 0; r < 4; ++r) part_s[chh][js * 16 + lgrp * 4 + r] = s[r];
        }
        __syncthreads();
        if (t < 128) sg[(size_t)blk * DH_ + t] = -(part_s[0][t] + part_s[1][t]) / g_s[t];
    }
}

// ---------------------------------------------------------------- all scans, one launch (bf16x8 vectorized)
__global__ __launch_bounds__(256) void scan_all(
    __bf16* __restrict__ sw1, const __bf16* __restrict__ w1T,
    __bf16* __restrict__ sw2, const __bf16* __restrict__ w2T,
    float* __restrict__ sgb, const float* __restrict__ memg,
    const float* __restrict__ beta, const float* __restrict__ alpha)
{
    const int bi = blockIdx.x, t = threadIdx.x;
    if (bi < 512) {
        __bf16* buf = (bi < 256) ? sw1 : sw2;
        const __bf16* init = (bi < 256) ? w1T : w2T;
        int idx = (bi & 255) * 256 + t;          // 0..65535
        int bh = idx >> 13, e8 = idx & 8191;     // 8192 el8-groups per bh
        size_t off = (size_t)e8 * 8;
        const float* bp = beta + bh * NC_;
        const float* ap = alpha + bh * NC_;
        __bf16* base = buf + (size_t)bh * NC_ * 65536 + off;
        bf16x8 iv = *(const bf16x8*)(init + off);
        float m[8], wv[8];
#pragma unroll
        for (int k = 0; k < 8; ++k) { m[k] = 0.f; wv[k] = (float)iv[k]; }
        for (int ci = 0; ci < NC_; ++ci) {
            bf16x8 s = *(const bf16x8*)(base + (size_t)ci * 65536);
            float bb = bp[ci], aa = ap[ci];
            bf16x8 o;
#pragma unroll
            for (int k = 0; k < 8; ++k) {
                o[k] = (__bf16)wv[k];
                m[k] = fmaf(bb, m[k], (float)s[k]);
                wv[k] = fmaf(aa, wv[k], m[k]);
            }
            *(bf16x8*)(base + (size_t)ci * 65536) = o;   // w_prev for this chunk
        }
    } else {
        int idx = (bi - 512) * 256 + t;   // < 1024
        int bh = idx >> 7, el = idx & 127;
        float wv = memg[el], m = 0.f;
        const float* bp = beta + bh * NC_;
        const float* ap = alpha + bh * NC_;
        float* base = sgb + ((size_t)bh * NC_) * 128 + el;
        for (int ci = 0; ci < NC_; ++ci) {
            float s = base[(size_t)ci * 128];
            base[(size_t)ci * 128] = wv;
            m = fmaf(bp[ci], m, s);
            wv = fmaf(ap[ci], wv, m);
        }
    }
}

// ---------------------------------------------------------------- retrieval (MFMA forward, 8 waves) + gate
__global__ __launch_bounds__(512, 4) void retrieve_kernel(
    const float* __restrict__ qbuf, const float* __restrict__ gatebuf,
    const float* __restrict__ sg, const __bf16* __restrict__ sw1,
    const __bf16* __restrict__ sw2, __bf16* __restrict__ retgb)
{
    const int blk = blockIdx.x;
    const int t = threadIdx.x;
    const int w = t >> 6, lane = t & 63;
    const int lrow = lane & 15, lgrp = lane >> 4;
    const int bh = blk >> 5, nc = blk & 31;
    const float* qc = qbuf + (size_t)blk * (CH_ * DH_);
    const __bf16* w1p = sw1 + (size_t)blk * (DHID_ * DH_);
    const __bf16* w2p = sw2 + (size_t)blk * (DHID_ * DH_);
    const float* gp = sg + (size_t)blk * DH_;

    __shared__ __bf16 h_s[64][136];
    __shared__ __bf16 a_s[64][136];
    __shared__ float g_s[128];

    if (t < 128) g_s[t] = gp[t];
    {
        const int c = t >> 3, dblk = t & 7, d0 = dblk * 16;
        float xv[16];
        float ss = 0.f;
#pragma unroll
        for (int i = 0; i < 4; ++i) {
            float4 f = *(const float4*)(qc + (size_t)c * DH_ + d0 + i * 4);
            xv[i * 4 + 0] = f.x; xv[i * 4 + 1] = f.y; xv[i * 4 + 2] = f.z; xv[i * 4 + 3] = f.w;
            ss += f.x * f.x + f.y * f.y + f.z * f.z + f.w * f.w;
        }
        ss += __shfl_xor(ss, 1); ss += __shfl_xor(ss, 2); ss += __shfl_xor(ss, 4);
        float r = rsqrtf(ss * (1.0f / DH_) + 1e-6f);
        __syncthreads();   // g_s visible
#pragma unroll
        for (int i = 0; i < 16; ++i)
            h_s[c][d0 + i] = (__bf16)(xv[i] * r * g_s[d0 + i]);
    }
    __syncthreads();

    const int cs = w & 3, dh2 = w >> 2;
    const int c0w = cs * 16, d0w = dh2 * 64;
    f32x4 yacc[4];
#pragma unroll
    for (int i = 0; i < 4; ++i) yacc[i] = (f32x4)0.f;

    for (int jt = 0; jt < 4; ++jt) {
        f32x4 zacc[4];
#pragma unroll
        for (int i = 0; i < 4; ++i) zacc[i] = (f32x4)0.f;
#pragma unroll
        for (int kt = 0; kt < 4; ++kt) {
            bf16x8 av = ld8(&h_s[c0w + lrow][kt * 32 + lgrp * 8]);
#pragma unroll
            for (int ct = 0; ct < 4; ++ct) {
                int j = jt * 128 + d0w + ct * 16 + lrow;
                bf16x8 bv = ld8(w1p + (size_t)j * 128 + kt * 32 + lgrp * 8);
                zacc[ct] = MFMA(av, bv, zacc[ct]);
            }
        }
#pragma unroll
        for (int ct = 0; ct < 4; ++ct)
#pragma unroll
            for (int r = 0; r < 4; ++r)
                a_s[c0w + lgrp * 4 + r][d0w + ct * 16 + lrow] = (__bf16)gelu_f(zacc[ct][r]);
        __syncthreads();
#pragma unroll
        for (int kt = 0; kt < 4; ++kt) {
            bf16x8 av = ld8(&a_s[c0w + lrow][kt * 32 + lgrp * 8]);
#pragma unroll
            for (int ct = 0; ct < 4; ++ct) {
                int d = d0w + ct * 16 + lrow;
                bf16x8 bv = ld8(w2p + (size_t)d * 512 + jt * 128 + kt * 32 + lgrp * 8);
                yacc[ct] = MFMA(av, bv, yacc[ct]);
            }
        }
        __syncthreads();
    }
    const int b = bh >> 2, hh = bh & 3;
#pragma unroll
    for (int ct = 0; ct < 4; ++ct)
#pragma unroll
        for (int r = 0; r < 4; ++r) {
            int c = c0w + lgrp * 4 + r, d = d0w + ct * 16 + lrow;
            int n = nc * CH_ + c;
            float q = qc[(size_t)c * DH_ + d];
            float gv = gatebuf[(size_t)bh * N_ + n];
            retgb[((size_t)(b * N_ + n)) * 512 + hh * 128 + d] = (__bf16)((yacc[ct][r] + q) * gv);
        }
}

// ---------------------------------------------------------------- launch
extern "C" void kernel_launch(void* const* d_in, const int* in_sizes, int n_in,
                              void* d_out, int out_size, void* d_ws, size_t ws_size,
                              hipStream_t stream) {
    const float* seq     = (const float*)d_in[0];
    const float* g_store = (const float*)d_in[1];
    const float* g_retr  = (const float*)d_in[2];
    const float* Wq = (const float*)d_in[3];
    const float* Wk = (const float*)d_in[4];
    const float* Wv = (const float*)d_in[5];
    const float* Wa = (const float*)d_in[6];
    const float* ba = (const float*)d_in[7];
    const float* Wm = (const float*)d_in[8];
    const float* Wd = (const float*)d_in[9];
    const float* bd = (const float*)d_in[10];
    const float* Wg = (const float*)d_in[11];
    const float* Wc = (const float*)d_in[12];
    const float* memg = (const float*)d_in[13];
    const float* w1 = (const float*)d_in[14];
    const float* w2 = (const float*)d_in[15];
    float* out = (float*)d_out;

    float* p = (float*)d_ws;
    float* xs = p;     p += (size_t)B_ * N_ * DIM_;
    float* kb = p;     p += (size_t)B_ * N_ * DIM_;
    float* vb = p;     p += (size_t)B_ * N_ * DIM_;
    float* qb = p;     p += (size_t)B_ * N_ * DIM_;
    float* lrb = p;    p += (size_t)BH_ * N_;
    float* gateb = p;  p += (size_t)BH_ * N_;
    float* beta = p;   p += BH_ * NC_;
    float* alpha = p;  p += BH_ * NC_;
    float* sgb = p;    p += (size_t)BH_ * NC_ * DH_;

    __bf16* bp_ = (__bf16*)p;
    __bf16* xsb = bp_;  bp_ += (size_t)B_ * N_ * DIM_;
    __bf16* xrb = bp_;  bp_ += (size_t)B_ * N_ * DIM_;
    __bf16* retgb = bp_; bp_ += (size_t)B_ * N_ * DIM_;
    __bf16* w1b = bp_;  bp_ += DH_ * DHID_;
    __bf16* w1Tb = bp_; bp_ += DH_ * DHID_;
    __bf16* w2b = bp_;  bp_ += DH_ * DHID_;
    __bf16* w2Tb = bp_; bp_ += DH_ * DHID_;
    __bf16* WqT = bp_;  bp_ += DIM_ * DIM_;
    __bf16* WkT = bp_;  bp_ += DIM_ * DIM_;
    __bf16* WvT = bp_;  bp_ += DIM_ * DIM_;
    __bf16* WcT = bp_;  bp_ += DIM_ * DIM_;
    __bf16* sw1b = bp_; bp_ += (size_t)BH_ * NC_ * DH_ * DHID_;
    __bf16* sw2b = bp_; bp_ += (size_t)BH_ * NC_ * DH_ * DHID_;

    rms_kernel<<<B_ * N_, 256, 0, stream>>>(seq, g_store, g_retr, Wa, ba, Wg,
                                            xs, xsb, xrb, lrb, gateb);
    ba_kernel<<<B_ * NC_, 256, 0, stream>>>(xs, Wm, Wd, bd, beta, alpha);
    prep_kernel<<<1024, 256, 0, stream>>>(w1, w2, Wq, Wk, Wv, Wc,
                                          w1b, w1Tb, w2b, w2Tb, WqT, WkT, WvT, WcT);
    proj_kernel<<<dim3(64, 8, 3), 256, 0, stream>>>(xsb, xrb, WqT, WkT, WvT, qb, kb, vb);
    grad_kernel<<<BH_ * NC_, 1024, 0, stream>>>(kb, vb, lrb, memg, w1b, w1Tb, w2b, w2Tb,
                                                sgb, sw1b, sw2b);
    scan_all<<<516, 256, 0, stream>>>(sw1b, w1Tb, sw2b, w2Tb, sgb, memg, beta, alpha);
    retrieve_kernel<<<BH_ * NC_, 512, 0, stream>>>(qb, gateb, sgb, sw1b, sw2b, retgb);
    gemm_out<<<dim3(64, 8), 256, 0, stream>>>(retgb, WcT, out);
}